// Round 2
// baseline (652.946 us; speedup 1.0000x reference)
//
#include <hip/hip_runtime.h>
#include <hip/hip_bf16.h>
#include <cstdint>

typedef __attribute__((ext_vector_type(8))) short bf16x8;
typedef __attribute__((ext_vector_type(4))) float f32x4;
typedef unsigned short u16;

constexpr int B = 2, S = 2048, D = 2048, H = 16, HD = 128;
constexpr int M = B * S;                 // 4096 rows
constexpr float SCALE = 0.08838834764831845f;  // 1/sqrt(128)

static __device__ __forceinline__ float b2f(u16 u) {
    union { float f; uint32_t i; } v; v.i = ((uint32_t)u) << 16; return v.f;
}
static __device__ __forceinline__ u16 f2b(float f) {
    union { float f; uint32_t i; } v; v.f = f;
    uint32_t x = v.i;
    return (u16)((x + 0x7FFFu + ((x >> 16) & 1u)) >> 16);
}

// ---------------- silu(x) f32 -> bf16 ----------------
__global__ __launch_bounds__(256) void silu_cast(const float* __restrict__ x,
                                                 u16* __restrict__ h, int n) {
    int i = (blockIdx.x * 256 + threadIdx.x) * 4;
    if (i >= n) return;
    float4 v = *(const float4*)(x + i);
    ushort4 o;
    o.x = f2b(v.x / (1.f + __expf(-v.x)));
    o.y = f2b(v.y / (1.f + __expf(-v.y)));
    o.z = f2b(v.z / (1.f + __expf(-v.z)));
    o.w = f2b(v.w / (1.f + __expf(-v.w)));
    *(ushort4*)(h + i) = o;
}

// ---------------- weight (K,N) f32 -> wT (N,K) bf16 ----------------
__global__ __launch_bounds__(256) void wcast(const float* __restrict__ w,
                                             u16* __restrict__ wT) {
    __shared__ float t[64][65];
    int tx = threadIdx.x & 63, ty = threadIdx.x >> 6;
    int kb = blockIdx.y * 64, nb = blockIdx.x * 64;
    for (int r = ty; r < 64; r += 4)
        t[r][tx] = w[(size_t)(kb + r) * D + nb + tx];
    __syncthreads();
    for (int r = ty; r < 64; r += 4)
        wT[(size_t)(nb + r) * D + kb + tx] = f2b(t[tx][r]);
}

// ---------------- GEMM: A(M,K) bf16 row-major  @  BT(N,K) bf16 row-major ----------------
template <bool F32OUT>
__global__ __launch_bounds__(256)
void gemm_bt(const u16* __restrict__ A, const u16* __restrict__ BT,
             void* __restrict__ out, int Mm, int Nn, int Kk) {
    constexpr int LDT = 40;  // 32 + 8 pad (80B rows, 16B aligned)
    __shared__ u16 As[128 * LDT];
    __shared__ u16 Bs[128 * LDT];
    const int tid = threadIdx.x;
    const int lane = tid & 63, w = tid >> 6;
    const int wm = w >> 1, wn = w & 1;
    const int l16 = lane & 15, lq = lane >> 4;
    const int m0 = blockIdx.y * 128, n0 = blockIdx.x * 128;
    f32x4 acc[4][4] = {};

    for (int k0 = 0; k0 < Kk; k0 += 32) {
        __syncthreads();
#pragma unroll
        for (int i = 0; i < 2; ++i) {
            int u = tid + i * 256;          // 512 16B units per operand: [128 rows][4 units]
            int row = u >> 2, col = (u & 3) * 8;
            *(int4*)(As + row * LDT + col) =
                *(const int4*)(A + (size_t)(m0 + row) * Kk + k0 + col);
            *(int4*)(Bs + row * LDT + col) =
                *(const int4*)(BT + (size_t)(n0 + row) * Kk + k0 + col);
        }
        __syncthreads();
        bf16x8 af[4], bfr[4];
#pragma unroll
        for (int mi = 0; mi < 4; mi++)
            af[mi] = *(const bf16x8*)(As + (wm * 64 + mi * 16 + l16) * LDT + lq * 8);
#pragma unroll
        for (int ni = 0; ni < 4; ni++)
            bfr[ni] = *(const bf16x8*)(Bs + (wn * 64 + ni * 16 + l16) * LDT + lq * 8);
#pragma unroll
        for (int mi = 0; mi < 4; mi++)
#pragma unroll
            for (int ni = 0; ni < 4; ni++)
                acc[mi][ni] = __builtin_amdgcn_mfma_f32_16x16x32_bf16(
                    af[mi], bfr[ni], acc[mi][ni], 0, 0, 0);
    }
#pragma unroll
    for (int mi = 0; mi < 4; mi++)
#pragma unroll
        for (int ni = 0; ni < 4; ni++)
#pragma unroll
            for (int r = 0; r < 4; r++) {
                int row = m0 + wm * 64 + mi * 16 + lq * 4 + r;
                int col = n0 + wn * 64 + ni * 16 + l16;
                float v = acc[mi][ni][r];
                if constexpr (F32OUT)
                    ((float*)out)[(size_t)row * Nn + col] = v;
                else
                    ((u16*)out)[(size_t)row * Nn + col] = f2b(v);
            }
}

// ---------------- RoPE(q,k): (B,S,H,HD) -> (B,H,S,HD) ----------------
__global__ __launch_bounds__(256)
void reformat(const u16* __restrict__ qb, const u16* __restrict__ kb,
              const float* __restrict__ fc, const float* __restrict__ fs,
              u16* __restrict__ qr, u16* __restrict__ kr) {
    int bh = blockIdx.x;           // 0..31
    int s0 = blockIdx.y * 64;
    int b = bh >> 4, h = bh & 15;
    int tid = threadIdx.x;
#pragma unroll
    for (int i = 0; i < 16; ++i) {
        int p = tid + i * 256;     // 4096 (row,pair) items: [64 rows][64 pairs]
        int row = p >> 6, pp = p & 63;
        int sgl = s0 + row;
        float c = fc[sgl * 64 + pp], sn = fs[sgl * 64 + pp];
        size_t src = (size_t)(b * S + sgl) * D + h * HD + 2 * pp;
        size_t dst = ((size_t)bh * S + sgl) * HD + 2 * pp;
        {
            uint32_t qv = *(const uint32_t*)(qb + src);
            float r = b2f((u16)(qv & 0xffff)), im = b2f((u16)(qv >> 16));
            uint32_t o = (uint32_t)f2b(r * c - im * sn) |
                         ((uint32_t)f2b(r * sn + im * c) << 16);
            *(uint32_t*)(qr + dst) = o;
        }
        {
            uint32_t kv = *(const uint32_t*)(kb + src);
            float r = b2f((u16)(kv & 0xffff)), im = b2f((u16)(kv >> 16));
            uint32_t o = (uint32_t)f2b(r * c - im * sn) |
                         ((uint32_t)f2b(r * sn + im * c) << 16);
            *(uint32_t*)(kr + dst) = o;
        }
    }
}

// ---------------- causal silu-attention ----------------
// q,k: (B,H,S,HD) bf16 (RoPE'd); v: (B,S,H,HD) bf16 (projection layout, transposed on stage)
__global__ __launch_bounds__(256)
void hstu_attn(const u16* __restrict__ qr, const u16* __restrict__ kr,
               const u16* __restrict__ vb, float* __restrict__ att) {
    int bh = blockIdx.y;
    int q0 = blockIdx.x * 128;
    int b = bh >> 4, h = bh & 15;
    int tid = threadIdx.x, lane = tid & 63, w = tid >> 6;
    int l16 = lane & 15, lq = lane >> 4;
    int wm = w >> 1, wn = w & 1;

    constexpr int LDK = 136;        // 128 + 8
    constexpr int LDV = 76;         // 64 + 12 (152B rows: conflict-free b128 reads)
    __shared__ u16 k_l[64 * LDK];   // [64 keys][128 d]
    __shared__ u16 v_l[128 * LDV];  // [128 d][64 s]
    __shared__ u16 s_l[128 * LDV];  // [128 q][64 k]

    // q fragments held in registers for the whole block
    bf16x8 qf[4][4];
#pragma unroll
    for (int mi = 0; mi < 4; mi++)
#pragma unroll
        for (int kk = 0; kk < 4; kk++)
            qf[mi][kk] = *(const bf16x8*)(qr + ((size_t)bh * S + q0 + wm * 64 + mi * 16 + l16) * HD +
                                          kk * 32 + lq * 8);

    f32x4 acco[4][4] = {};
    int nkt = q0 / 64 + 2;
    for (int kt = 0; kt < nkt; ++kt) {
        int k0 = kt * 64;
        __syncthreads();
#pragma unroll
        for (int i = 0; i < 4; ++i) {   // stage K tile [64 keys][128 d]
            int u = tid + i * 256;      // 1024 units: 16 units/row
            int row = u >> 4, cb = (u & 15) * 8;
            *(int4*)(k_l + row * LDK + cb) =
                *(const int4*)(kr + ((size_t)bh * S + k0 + row) * HD + cb);
        }
#pragma unroll
        for (int i = 0; i < 4; ++i) {   // stage V tile [64 s][128 d] -> v_l[d][s]
            int u = tid + i * 256;
            int srow = u >> 4, cb = (u & 15) * 8;
            u16 tmp[8];
            *(int4*)tmp = *(const int4*)(vb + (size_t)(b * S + k0 + srow) * D + h * HD + cb);
#pragma unroll
            for (int j = 0; j < 8; j++) v_l[(cb + j) * LDV + srow] = tmp[j];
        }
        __syncthreads();
        // S = q @ k^T  (wave: rows wm*64+[0,64), keys wn*32+[0,32))
        f32x4 accs[4][2] = {};
        bf16x8 kf[2][4];
#pragma unroll
        for (int ni = 0; ni < 2; ni++)
#pragma unroll
            for (int kk = 0; kk < 4; kk++)
                kf[ni][kk] = *(const bf16x8*)(k_l + (wn * 32 + ni * 16 + l16) * LDK + kk * 32 + lq * 8);
#pragma unroll
        for (int kk = 0; kk < 4; kk++)
#pragma unroll
            for (int mi = 0; mi < 4; mi++)
#pragma unroll
                for (int ni = 0; ni < 2; ni++)
                    accs[mi][ni] = __builtin_amdgcn_mfma_f32_16x16x32_bf16(
                        qf[mi][kk], kf[ni][kk], accs[mi][ni], 0, 0, 0);
        // scale + causal mask + silu -> s_l (bf16)
#pragma unroll
        for (int mi = 0; mi < 4; mi++)
#pragma unroll
            for (int ni = 0; ni < 2; ni++)
#pragma unroll
                for (int r = 0; r < 4; r++) {
                    int qrow = wm * 64 + mi * 16 + lq * 4 + r;
                    int krow = wn * 32 + ni * 16 + l16;
                    float vv = accs[mi][ni][r] * SCALE;
                    vv = (k0 + krow <= q0 + qrow) ? vv / (1.f + __expf(-vv)) : 0.f;
                    s_l[qrow * LDV + krow] = f2b(vv);
                }
        __syncthreads();
        // PV: out[128q][128d] += S[128][64] @ V[64][128] (wave: rows wm*64, cols wn*64)
#pragma unroll
        for (int kk = 0; kk < 2; kk++) {
            bf16x8 vf[4];
#pragma unroll
            for (int ni = 0; ni < 4; ni++)
                vf[ni] = *(const bf16x8*)(v_l + (wn * 64 + ni * 16 + l16) * LDV + kk * 32 + lq * 8);
#pragma unroll
            for (int mi = 0; mi < 4; mi++) {
                bf16x8 sf = *(const bf16x8*)(s_l + (wm * 64 + mi * 16 + l16) * LDV + kk * 32 + lq * 8);
#pragma unroll
                for (int ni = 0; ni < 4; ni++)
                    acco[mi][ni] = __builtin_amdgcn_mfma_f32_16x16x32_bf16(
                        sf, vf[ni], acco[mi][ni], 0, 0, 0);
            }
        }
    }
    // write att as (B,S,H,HD) f32
#pragma unroll
    for (int mi = 0; mi < 4; mi++)
#pragma unroll
        for (int ni = 0; ni < 4; ni++)
#pragma unroll
            for (int r = 0; r < 4; r++) {
                int qrow = q0 + wm * 64 + mi * 16 + lq * 4 + r;
                int d = wn * 64 + ni * 16 + l16;
                att[((size_t)(b * S + qrow) * H + h) * HD + d] = acco[mi][ni][r];
            }
}

// ---------------- RMS-norm * norm_w * u -> bf16 ----------------
__global__ __launch_bounds__(256)
void rms_mul(const float* __restrict__ att, const u16* __restrict__ ub,
             const float* __restrict__ nw, u16* __restrict__ outp) {
    int row = blockIdx.x;
    int tid = threadIdx.x;
    const float* a = att + (size_t)row * D + tid * 8;
    float4 v0 = *(const float4*)(a);
    float4 v1 = *(const float4*)(a + 4);
    float ss = v0.x * v0.x + v0.y * v0.y + v0.z * v0.z + v0.w * v0.w +
               v1.x * v1.x + v1.y * v1.y + v1.z * v1.z + v1.w * v1.w;
#pragma unroll
    for (int off = 32; off > 0; off >>= 1) ss += __shfl_down(ss, off, 64);
    __shared__ float red[4];
    int lane = tid & 63, w = tid >> 6;
    if (lane == 0) red[w] = ss;
    __syncthreads();
    float rs = rsqrtf((red[0] + red[1] + red[2] + red[3]) * (1.f / D) + 1e-5f);
    int col = tid * 8;
    u16 ut[8];
    *(int4*)ut = *(const int4*)(ub + (size_t)row * D + col);
    float f[8] = {v0.x, v0.y, v0.z, v0.w, v1.x, v1.y, v1.z, v1.w};
    u16 o[8];
#pragma unroll
    for (int j = 0; j < 8; j++)
        o[j] = f2b(f[j] * rs * nw[col + j] * b2f(ut[j]));
    *(int4*)(outp + (size_t)row * D + col) = *(int4*)o;
}

extern "C" void kernel_launch(void* const* d_in, const int* in_sizes, int n_in,
                              void* d_out, int out_size, void* d_ws, size_t ws_size,
                              hipStream_t stream) {
    const float* x  = (const float*)d_in[0];
    const float* fc = (const float*)d_in[1];
    const float* fs = (const float*)d_in[2];
    const float* wq = (const float*)d_in[3];
    const float* wk = (const float*)d_in[4];
    const float* wv = (const float*)d_in[5];
    const float* wu = (const float*)d_in[6];
    const float* wo = (const float*)d_in[7];
    const float* nw = (const float*)d_in[8];
    float* out = (float*)d_out;

    char* ws = (char*)d_ws;
    const size_t SZ  = (size_t)M * D * sizeof(u16);  // 16.78 MB
    const size_t WSZ = (size_t)D * D * sizeof(u16);  // 8.39 MB
    u16* h_b = (u16*)(ws);
    u16* q_b = (u16*)(ws + SZ);
    u16* k_b = (u16*)(ws + 2 * SZ);
    u16* v_b = (u16*)(ws + 3 * SZ);
    u16* u_b = (u16*)(ws + 4 * SZ);
    u16* wT  = (u16*)(ws + 5 * SZ);                  // 5 weights
    u16* k_r = (u16*)(ws + 5 * SZ + 5 * WSZ);
    // reuse (consumed buffers):
    u16* q_r = h_b;             // rope output overlays h (h consumed by the 4 GEMMs)
    float* att = (float*)q_b;   // attention out overlays q_b+k_b (33.55 MB)
    u16* normed = v_b;          // normed overlays v_b (v consumed by hstu_attn)

    silu_cast<<<8192, 256, 0, stream>>>(x, h_b, M * D);
    dim3 wg(32, 32);
    wcast<<<wg, 256, 0, stream>>>(wq, wT + 0 * (size_t)D * D);
    wcast<<<wg, 256, 0, stream>>>(wk, wT + 1 * (size_t)D * D);
    wcast<<<wg, 256, 0, stream>>>(wv, wT + 2 * (size_t)D * D);
    wcast<<<wg, 256, 0, stream>>>(wu, wT + 3 * (size_t)D * D);
    wcast<<<wg, 256, 0, stream>>>(wo, wT + 4 * (size_t)D * D);

    dim3 gg(D / 128, M / 128);  // (16, 32)
    gemm_bt<false><<<gg, 256, 0, stream>>>(h_b, wT + 0 * (size_t)D * D, q_b, M, D, D);
    gemm_bt<false><<<gg, 256, 0, stream>>>(h_b, wT + 1 * (size_t)D * D, k_b, M, D, D);
    gemm_bt<false><<<gg, 256, 0, stream>>>(h_b, wT + 2 * (size_t)D * D, v_b, M, D, D);
    gemm_bt<false><<<gg, 256, 0, stream>>>(h_b, wT + 3 * (size_t)D * D, u_b, M, D, D);

    reformat<<<dim3(32, 32), 256, 0, stream>>>(q_b, k_b, fc, fs, q_r, k_r);
    hstu_attn<<<dim3(16, 32), 256, 0, stream>>>(q_r, k_r, v_b, att);
    rms_mul<<<M, 256, 0, stream>>>(att, u_b, nw, normed);
    gemm_bt<true><<<gg, 256, 0, stream>>>(normed, wT + 4 * (size_t)D * D, out, M, D, D);
}

// Round 4
// 423.091 us; speedup vs baseline: 1.5433x; 1.5433x over previous
//
#include <hip/hip_runtime.h>
#include <hip/hip_bf16.h>
#include <cstdint>

typedef __attribute__((ext_vector_type(8))) short bf16x8;
typedef __attribute__((ext_vector_type(4))) float f32x4;
typedef unsigned short u16;

constexpr int B = 2, S = 2048, D = 2048, H = 16, HD = 128;
constexpr int M = B * S;                 // 4096 rows
constexpr int NQKU = 6144;               // q,k,u fused N
constexpr int ATT_LD = 3072;             // f32 row stride of att overlay (= 6144 u16)
constexpr float SCALE = 0.08838834764831845f;  // 1/sqrt(128)

static __device__ __forceinline__ float b2f(u16 u) {
    union { float f; uint32_t i; } v; v.i = ((uint32_t)u) << 16; return v.f;
}
static __device__ __forceinline__ u16 f2b(float f) {
    union { float f; uint32_t i; } v; v.f = f;
    uint32_t x = v.i;
    return (u16)((x + 0x7FFFu + ((x >> 16) & 1u)) >> 16);
}

__device__ __forceinline__ void gll16(const void* g, void* l) {
    __builtin_amdgcn_global_load_lds(
        (const __attribute__((address_space(1))) uint32_t*)g,
        (__attribute__((address_space(3))) uint32_t*)l, 16, 0, 0);
}

// ---------------- silu(x) f32 -> bf16 ----------------
__global__ __launch_bounds__(256) void silu_cast(const float* __restrict__ x,
                                                 u16* __restrict__ h, int n) {
    int i = (blockIdx.x * 256 + threadIdx.x) * 4;
    if (i >= n) return;
    float4 v = *(const float4*)(x + i);
    ushort4 o;
    o.x = f2b(v.x / (1.f + __expf(-v.x)));
    o.y = f2b(v.y / (1.f + __expf(-v.y)));
    o.z = f2b(v.z / (1.f + __expf(-v.z)));
    o.w = f2b(v.w / (1.f + __expf(-v.w)));
    *(ushort4*)(h + i) = o;
}

// ---------------- weight (K,N) f32 -> wT (N,K) bf16 ----------------
__global__ __launch_bounds__(256) void wcast(const float* __restrict__ w,
                                             u16* __restrict__ wT) {
    __shared__ float t[64][65];
    int tx = threadIdx.x & 63, ty = threadIdx.x >> 6;
    int kb = blockIdx.y * 64, nb = blockIdx.x * 64;
    for (int r = ty; r < 64; r += 4)
        t[r][tx] = w[(size_t)(kb + r) * D + nb + tx];
    __syncthreads();
    for (int r = ty; r < 64; r += 4)
        wT[(size_t)(nb + r) * D + kb + tx] = f2b(t[tx][r]);
}

// ---------------- GEMM (m97 structure): A(M,K) bf16 @ BT(N,K) bf16 ----------------
// OMODE 0: bf16 out (ldc);  1: f32 out (ldc);  2: transposed scatter to vt (B,H,HD,S)
template <int OMODE>
__global__ __launch_bounds__(256)
void gemm_bt(const u16* __restrict__ A, const u16* __restrict__ BT,
             void* __restrict__ out, int lda, int ldc, int Kk) {
    __shared__ u16 As[128 * 32];
    __shared__ u16 Bs[128 * 32];
    const int tid = threadIdx.x;
    const int lane = tid & 63, w = tid >> 6;
    const int wm = w >> 1, wn = w & 1;
    const int l16 = lane & 15, lq = lane >> 4;
    const int m0 = blockIdx.y * 128, n0 = blockIdx.x * 128;
    const int rs = lane >> 2;           // staging row 0..15
    const int cs = (lane & 3) * 8;      // staging col (u16)
    f32x4 acc[4][4] = {};

    const u16* Ab = A + (size_t)(m0 + w * 32 + rs) * lda + cs;
    const u16* Bb = BT + (size_t)(n0 + w * 32 + rs) * Kk + cs;
    u16* Al = As + w * 32 * 32;
    u16* Bl = Bs + w * 32 * 32;

    for (int k0 = 0; k0 < Kk; k0 += 32) {
        gll16(Ab + k0, Al);
        gll16(Ab + k0 + (size_t)16 * lda, Al + 16 * 32);
        gll16(Bb + k0, Bl);
        gll16(Bb + k0 + (size_t)16 * Kk, Bl + 16 * 32);
        __syncthreads();
        bf16x8 af[4], bfr[4];
#pragma unroll
        for (int mi = 0; mi < 4; mi++)
            af[mi] = *(const bf16x8*)(As + (wm * 64 + mi * 16 + l16) * 32 + lq * 8);
#pragma unroll
        for (int ni = 0; ni < 4; ni++)
            bfr[ni] = *(const bf16x8*)(Bs + (wn * 64 + ni * 16 + l16) * 32 + lq * 8);
#pragma unroll
        for (int mi = 0; mi < 4; mi++)
#pragma unroll
            for (int ni = 0; ni < 4; ni++)
                acc[mi][ni] = __builtin_amdgcn_mfma_f32_16x16x32_bf16(
                    af[mi], bfr[ni], acc[mi][ni], 0, 0, 0);
        __syncthreads();
    }
#pragma unroll
    for (int mi = 0; mi < 4; mi++)
#pragma unroll
        for (int ni = 0; ni < 4; ni++) {
            if constexpr (OMODE == 2) {
                int col = n0 + wn * 64 + ni * 16 + l16;        // 0..2047
                int hh = col >> 7, d = col & 127;
                int row0 = m0 + wm * 64 + mi * 16 + lq * 4;
                int bb = row0 >> 11, s0 = row0 & 2047;
                ushort4 pk = make_ushort4(f2b(acc[mi][ni][0]), f2b(acc[mi][ni][1]),
                                          f2b(acc[mi][ni][2]), f2b(acc[mi][ni][3]));
                *(ushort4*)((u16*)out + (((size_t)(bb * H + hh) * HD + d) * S + s0)) = pk;
            } else {
#pragma unroll
                for (int r = 0; r < 4; r++) {
                    int row = m0 + wm * 64 + mi * 16 + lq * 4 + r;
                    int col = n0 + wn * 64 + ni * 16 + l16;
                    float v = acc[mi][ni][r];
                    if constexpr (OMODE == 1)
                        ((float*)out)[(size_t)row * ldc + col] = v;
                    else
                        ((u16*)out)[(size_t)row * ldc + col] = f2b(v);
                }
            }
        }
}

// ---------------- RoPE(q,k): qku cols -> (B,H,S,HD) ----------------
__global__ __launch_bounds__(256)
void reformat(const u16* __restrict__ qku, const float* __restrict__ fc,
              const float* __restrict__ fs, u16* __restrict__ qr,
              u16* __restrict__ kr) {
    int bh = blockIdx.x;           // 0..31
    int s0 = blockIdx.y * 64;
    int b = bh >> 4, h = bh & 15;
    int tid = threadIdx.x;
#pragma unroll
    for (int i = 0; i < 16; ++i) {
        int p = tid + i * 256;     // [64 rows][64 pairs]
        int row = p >> 6, pp = p & 63;
        int sgl = s0 + row;
        float c = fc[sgl * 64 + pp], sn = fs[sgl * 64 + pp];
        size_t src = (size_t)(b * S + sgl) * NQKU + h * HD + 2 * pp;
        size_t dst = ((size_t)bh * S + sgl) * HD + 2 * pp;
        {
            uint32_t qv = *(const uint32_t*)(qku + src);
            float r = b2f((u16)(qv & 0xffff)), im = b2f((u16)(qv >> 16));
            uint32_t o = (uint32_t)f2b(r * c - im * sn) |
                         ((uint32_t)f2b(r * sn + im * c) << 16);
            *(uint32_t*)(qr + dst) = o;
        }
        {
            uint32_t kv = *(const uint32_t*)(qku + src + 2048);
            float r = b2f((u16)(kv & 0xffff)), im = b2f((u16)(kv >> 16));
            uint32_t o = (uint32_t)f2b(r * c - im * sn) |
                         ((uint32_t)f2b(r * sn + im * c) << 16);
            *(uint32_t*)(kr + dst) = o;
        }
    }
}

// ---------------- causal silu-attention, QBLK=64, paired tiles (t, 31-t) ----------------
__global__ __launch_bounds__(256)
void hstu_attn(const u16* __restrict__ qr, const u16* __restrict__ kr,
               const u16* __restrict__ vt, float* __restrict__ att) {
    const int bh = blockIdx.y, slot = blockIdx.x;   // slot 0..15
    const int b = bh >> 4, h = bh & 15;
    const int tid = threadIdx.x, lane = tid & 63, w = tid >> 6;
    const int l16 = lane & 15, lq = lane >> 4;
    const int wm = w >> 1, wn = w & 1;
    constexpr int LDK = 136, LDV = 72, LDS_ = 72;
    __shared__ u16 k_l[64 * LDK];    // [64 k][128 d]
    __shared__ u16 v_l[128 * LDV];   // [128 d][64 s]
    __shared__ u16 s_l[64 * LDS_];   // [64 q][64 k]

    for (int pass = 0; pass < 2; ++pass) {
        const int t = pass ? (31 - slot) : slot;
        const int q0 = t * 64;
        bf16x8 qf[2][4];
#pragma unroll
        for (int mi = 0; mi < 2; mi++)
#pragma unroll
            for (int kk = 0; kk < 4; kk++)
                qf[mi][kk] = *(const bf16x8*)(qr +
                    ((size_t)bh * S + q0 + wm * 32 + mi * 16 + l16) * HD + kk * 32 + lq * 8);
        f32x4 acco[2][4] = {};

        for (int kt = 0; kt <= t; ++kt) {
            const int k0 = kt * 64;
            __syncthreads();
#pragma unroll
            for (int i = 0; i < 4; ++i) {   // K tile [64 k][128 d]
                int u = tid + i * 256;      // 16 units/row
                int row = u >> 4, cb = (u & 15) * 8;
                *(int4*)(k_l + row * LDK + cb) =
                    *(const int4*)(kr + ((size_t)bh * S + k0 + row) * HD + cb);
            }
#pragma unroll
            for (int i = 0; i < 4; ++i) {   // V^T tile [128 d][64 s]
                int u = tid + i * 256;      // 8 units/row
                int row = u >> 3, cb = (u & 7) * 8;
                *(int4*)(v_l + row * LDV + cb) =
                    *(const int4*)(vt + ((size_t)bh * HD + row) * S + k0 + cb);
            }
            __syncthreads();
            // S = q@k^T: wave (wm: 32 q rows, wn: 32 k cols)
            f32x4 accs[2][2] = {};
            bf16x8 kf[2][4];
#pragma unroll
            for (int ni = 0; ni < 2; ni++)
#pragma unroll
                for (int kk = 0; kk < 4; kk++)
                    kf[ni][kk] = *(const bf16x8*)(k_l + (wn * 32 + ni * 16 + l16) * LDK +
                                                  kk * 32 + lq * 8);
#pragma unroll
            for (int kk = 0; kk < 4; kk++)
#pragma unroll
                for (int mi = 0; mi < 2; mi++)
#pragma unroll
                    for (int ni = 0; ni < 2; ni++)
                        accs[mi][ni] = __builtin_amdgcn_mfma_f32_16x16x32_bf16(
                            qf[mi][kk], kf[ni][kk], accs[mi][ni], 0, 0, 0);
            const bool dg = (kt == t);
#pragma unroll
            for (int mi = 0; mi < 2; mi++)
#pragma unroll
                for (int ni = 0; ni < 2; ni++)
#pragma unroll
                    for (int r = 0; r < 4; r++) {
                        int qrow = wm * 32 + mi * 16 + lq * 4 + r;
                        int krow = wn * 32 + ni * 16 + l16;
                        float vv = accs[mi][ni][r] * SCALE;
                        vv = (!dg || krow <= qrow) ? vv / (1.f + __expf(-vv)) : 0.f;
                        s_l[qrow * LDS_ + krow] = f2b(vv);
                    }
            __syncthreads();
            // PV: out[64 q][128 d] += S[64][64] @ V[64][128]; wave (wm: 32 q, wn: 64 d)
#pragma unroll
            for (int kk = 0; kk < 2; kk++) {
                bf16x8 vf[4];
#pragma unroll
                for (int ni = 0; ni < 4; ni++)
                    vf[ni] = *(const bf16x8*)(v_l + (wn * 64 + ni * 16 + l16) * LDV +
                                              kk * 32 + lq * 8);
#pragma unroll
                for (int mi = 0; mi < 2; mi++) {
                    bf16x8 sf = *(const bf16x8*)(s_l + (wm * 32 + mi * 16 + l16) * LDS_ +
                                                 kk * 32 + lq * 8);
#pragma unroll
                    for (int ni = 0; ni < 4; ni++)
                        acco[mi][ni] = __builtin_amdgcn_mfma_f32_16x16x32_bf16(
                            sf, vf[ni], acco[mi][ni], 0, 0, 0);
                }
            }
        }
        // store att rows (f32, stride ATT_LD)
#pragma unroll
        for (int mi = 0; mi < 2; mi++)
#pragma unroll
            for (int ni = 0; ni < 4; ni++)
#pragma unroll
                for (int r = 0; r < 4; r++) {
                    int qrow = q0 + wm * 32 + mi * 16 + lq * 4 + r;
                    int d = wn * 64 + ni * 16 + l16;
                    att[(size_t)(b * S + qrow) * ATT_LD + h * HD + d] = acco[mi][ni][r];
                }
    }
}

// ---------------- RMS-norm * norm_w * u (in place over u cols of qku) ----------------
__global__ __launch_bounds__(256)
void rms_mul(const float* __restrict__ att, u16* __restrict__ qku,
             const float* __restrict__ nw) {
    int row = blockIdx.x;
    int tid = threadIdx.x;
    const float* a = att + (size_t)row * ATT_LD + tid * 8;
    float4 v0 = *(const float4*)(a);
    float4 v1 = *(const float4*)(a + 4);
    float ss = v0.x * v0.x + v0.y * v0.y + v0.z * v0.z + v0.w * v0.w +
               v1.x * v1.x + v1.y * v1.y + v1.z * v1.z + v1.w * v1.w;
#pragma unroll
    for (int off = 32; off > 0; off >>= 1) ss += __shfl_down(ss, off, 64);
    __shared__ float red[4];
    int lane = tid & 63, w = tid >> 6;
    if (lane == 0) red[w] = ss;
    __syncthreads();
    float rs = rsqrtf((red[0] + red[1] + red[2] + red[3]) * (1.f / D) + 1e-5f);
    int col = tid * 8;
    u16* up = qku + (size_t)row * NQKU + 4096 + col;
    u16 ut[8];
    *(int4*)ut = *(const int4*)up;
    float f[8] = {v0.x, v0.y, v0.z, v0.w, v1.x, v1.y, v1.z, v1.w};
    u16 o[8];
#pragma unroll
    for (int j = 0; j < 8; j++)
        o[j] = f2b(f[j] * rs * nw[col + j] * b2f(ut[j]));
    *(int4*)up = *(int4*)o;
}

extern "C" void kernel_launch(void* const* d_in, const int* in_sizes, int n_in,
                              void* d_out, int out_size, void* d_ws, size_t ws_size,
                              hipStream_t stream) {
    const float* x  = (const float*)d_in[0];
    const float* fc = (const float*)d_in[1];
    const float* fs = (const float*)d_in[2];
    const float* wq = (const float*)d_in[3];
    const float* wk = (const float*)d_in[4];
    const float* wv = (const float*)d_in[5];
    const float* wu = (const float*)d_in[6];
    const float* wo = (const float*)d_in[7];
    const float* nw = (const float*)d_in[8];
    float* out = (float*)d_out;

    char* ws = (char*)d_ws;
    const size_t WSZ = (size_t)D * D * sizeof(u16);      // 8.39 MB
    // layout (units of WSZ): h_b[0,2) wT[2,7) qku[7,13) vt[13,15) k_r[15,17)
    u16* h_b  = (u16*)(ws);
    u16* wT   = (u16*)(ws + 2 * WSZ);
    u16* qku  = (u16*)(ws + 7 * WSZ);                    // M x 6144 = 6*WSZ
    u16* vt   = (u16*)(ws + 13 * WSZ);                   // (B,H,HD,S) = 2*WSZ
    u16* k_r  = (u16*)(ws + 15 * WSZ);                   // (B,H,S,HD) = 2*WSZ
    u16* q_r  = h_b;                                     // overlay (h consumed by GEMMs)
    float* att = (float*)qku;                            // overlay q+k cols as f32 (stride 3072)

    silu_cast<<<M * D / 1024, 256, 0, stream>>>(x, h_b, M * D);
    dim3 wg(32, 32);
    wcast<<<wg, 256, 0, stream>>>(wq, wT + 0 * (size_t)D * D);
    wcast<<<wg, 256, 0, stream>>>(wk, wT + 1 * (size_t)D * D);
    wcast<<<wg, 256, 0, stream>>>(wu, wT + 2 * (size_t)D * D);
    wcast<<<wg, 256, 0, stream>>>(wv, wT + 3 * (size_t)D * D);
    wcast<<<wg, 256, 0, stream>>>(wo, wT + 4 * (size_t)D * D);

    // fused Q,K,U GEMM -> qku (bf16, ldc=6144)
    gemm_bt<0><<<dim3(NQKU / 128, M / 128), 256, 0, stream>>>(
        h_b, wT, qku, D, NQKU, D);
    // V GEMM with transposed epilogue -> vt (B,H,HD,S)
    gemm_bt<2><<<dim3(D / 128, M / 128), 256, 0, stream>>>(
        h_b, wT + 3 * (size_t)D * D, vt, D, 0, D);

    reformat<<<dim3(32, 32), 256, 0, stream>>>(qku, fc, fs, q_r, k_r);
    hstu_attn<<<dim3(16, 32), 256, 0, stream>>>(q_r, k_r, vt, att);
    rms_mul<<<M, 256, 0, stream>>>(att, qku, nw);
    // out = normed(u cols of qku) @ wo^T  (f32 out)
    gemm_bt<1><<<dim3(D / 128, M / 128), 256, 0, stream>>>(
        qku + 4096, wT + 4 * (size_t)D * D, out, NQKU, D, D);
}

// Round 5
// 366.338 us; speedup vs baseline: 1.7824x; 1.1549x over previous
//
#include <hip/hip_runtime.h>
#include <hip/hip_bf16.h>
#include <cstdint>

typedef __attribute__((ext_vector_type(8))) short bf16x8;
typedef __attribute__((ext_vector_type(4))) float f32x4;
typedef unsigned short u16;

constexpr int B = 2, S = 2048, D = 2048, H = 16, HD = 128;
constexpr int M = B * S;                 // 4096 rows
constexpr int NQKU = 6144;               // q,k,u stored cols
constexpr int ATT_LD = 3072;             // f32 row stride of att overlay (= 6144 u16)
constexpr float SCALE = 0.08838834764831845f;  // 1/sqrt(128)

static __device__ __forceinline__ float b2f(u16 u) {
    union { float f; uint32_t i; } v; v.i = ((uint32_t)u) << 16; return v.f;
}
static __device__ __forceinline__ u16 f2b(float f) {
    union { float f; uint32_t i; } v; v.f = f;
    uint32_t x = v.i;
    return (u16)((x + 0x7FFFu + ((x >> 16) & 1u)) >> 16);
}

__device__ __forceinline__ void gll16(const void* g, void* l) {
    __builtin_amdgcn_global_load_lds(
        (const __attribute__((address_space(1))) uint32_t*)g,
        (__attribute__((address_space(3))) uint32_t*)l, 16, 0, 0);
}

#define BAR() do { asm volatile("" ::: "memory"); __builtin_amdgcn_s_barrier(); \
                   asm volatile("" ::: "memory"); } while (0)

// ---------------- silu(x) f32 -> bf16 ----------------
__global__ __launch_bounds__(256) void silu_cast(const float* __restrict__ x,
                                                 u16* __restrict__ h, int n) {
    int i = (blockIdx.x * 256 + threadIdx.x) * 4;
    if (i >= n) return;
    float4 v = *(const float4*)(x + i);
    ushort4 o;
    o.x = f2b(v.x / (1.f + __expf(-v.x)));
    o.y = f2b(v.y / (1.f + __expf(-v.y)));
    o.z = f2b(v.z / (1.f + __expf(-v.z)));
    o.w = f2b(v.w / (1.f + __expf(-v.w)));
    *(ushort4*)(h + i) = o;
}

// ---------------- weight (K,N) f32 -> wT (N,K) bf16 ----------------
__global__ __launch_bounds__(256) void wcast(const float* __restrict__ w,
                                             u16* __restrict__ wT) {
    __shared__ float t[64][65];
    int tx = threadIdx.x & 63, ty = threadIdx.x >> 6;
    int kb = blockIdx.y * 64, nb = blockIdx.x * 64;
    for (int r = ty; r < 64; r += 4)
        t[r][tx] = w[(size_t)(kb + r) * D + nb + tx];
    __syncthreads();
    for (int r = ty; r < 64; r += 4)
        wT[(size_t)(nb + r) * D + kb + tx] = f2b(t[tx][r]);
}

// ============ fused QKUV GEMM: 256x256 tile, BK=64, 8 waves, 8-phase ============
// A: h (M x 2048). BT: wT rows [q|k|u|v] (8192 x 2048).
// cols < 6144 -> qku (ldc 6144, bf16); cols >= 6144 -> vt (B,H,HD,S) scatter.
__global__ __launch_bounds__(512, 2)
void gemm_qkuv(const u16* __restrict__ A, const u16* __restrict__ BT,
               u16* __restrict__ qku, u16* __restrict__ vt) {
    __shared__ u16 lds[65536];  // 128 KiB: A0|B0|A1|B1 (32KB each)
    const int tid = threadIdx.x;
    const int lane = tid & 63, wid = tid >> 6;
    const int wm = wid >> 2, wn = wid & 3;       // 2 x 4 waves
    const int l16 = lane & 15, lq = lane >> 4;

    // XCD-aware swizzle: 512 blocks, 8 XCDs, 64 consecutive ids per XCD
    const int orig = blockIdx.x;
    const int swz = (orig & 7) * 64 + (orig >> 3);
    const int mt = swz & 15, nt = swz >> 4;      // 16 m-tiles x 32 n-tiles
    const int m0 = mt * 256, n0 = nt * 256;

    // staging invariants: thread t covers row srow, swizzled col chunk ce
    const int srow = tid >> 2;                                   // 0..127
    const int ce = ((tid & 3) * 8) ^ (((tid >> 5) & 1) << 4);    // elems
    // frag-read swizzle: XOR byte-bit5 with row-bit3
    const int rdx = (lq * 16) ^ (((l16 >> 3) & 1) << 5);         // bytes

    const u16* As0 = A + (size_t)(m0 + srow) * D + ce;
    const u16* Bs0 = BT + (size_t)(n0 + srow) * D + ce;

    // prologue: stage tile 0 -> buf0 (order: A.kb0 h01, B.kb0 h01, A.kb1 h01, B.kb1 h01)
    {
        u16* dA = lds + wid * 512;
        u16* dB = lds + 16384 + wid * 512;
        gll16(As0,                    dA);
        gll16(As0 + (size_t)128 * D,  dA + 8192);
        gll16(Bs0,                    dB);
        gll16(Bs0 + (size_t)128 * D,  dB + 8192);
        gll16(As0 + 32,                    dA + 4096);
        gll16(As0 + 32 + (size_t)128 * D,  dA + 8192 + 4096);
        gll16(Bs0 + 32,                    dB + 4096);
        gll16(Bs0 + 32 + (size_t)128 * D,  dB + 8192 + 4096);
    }
    asm volatile("s_waitcnt vmcnt(4)" ::: "memory");
    BAR();

    f32x4 acc[8][4] = {};
    bf16x8 a[8];
    const int rbB = (wn & 1) * 4096;  // byte row-base within B half

#define LOAD_A(kk)                                                            \
    _Pragma("unroll") for (int mi = 0; mi < 8; ++mi)                          \
        a[mi] = *(const bf16x8*)(Abase + (kk) * 8192 +                        \
                                 (mi * 16 + l16) * 64 + rdx);
#define LOAD_B(dst, nia, kk)                                                  \
    dst = *(const bf16x8*)(Bbase + (kk) * 8192 + rbB +                        \
                           ((nia) * 16 + l16) * 64 + rdx);
#define MFMA2(n0i, n1i)                                                       \
    __builtin_amdgcn_s_setprio(1);                                            \
    _Pragma("unroll") for (int mi = 0; mi < 8; ++mi) {                        \
        acc[mi][n0i] = __builtin_amdgcn_mfma_f32_16x16x32_bf16(a[mi], b0,     \
                            acc[mi][n0i], 0, 0, 0);                           \
        acc[mi][n1i] = __builtin_amdgcn_mfma_f32_16x16x32_bf16(a[mi], b1,     \
                            acc[mi][n1i], 0, 0, 0);                           \
    }                                                                          \
    __builtin_amdgcn_s_setprio(0);

    for (int kt = 0; kt < 32; ++kt) {
        const int buf = kt & 1;
        const char* Abase = (const char*)lds + buf * 65536 + wm * 16384;
        const char* Bbase = (const char*)lds + 32768 + buf * 65536 + (wn >> 1) * 16384;
        const bool st = (kt + 1) < 32;
        const u16* Asrc = As0 + (kt + 1) * 64;
        const u16* Bsrc = Bs0 + (kt + 1) * 64;
        u16* dA = lds + (buf ^ 1) * 32768 + wid * 512;
        u16* dB = dA + 16384;
        bf16x8 b0, b1;

        // ---- P0: A kk0 (8) + B ni0-1 kk0 (2); stage A.kb0 ----
        LOAD_A(0);
        LOAD_B(b0, 0, 0);
        LOAD_B(b1, 1, 0);
        if (st) { gll16(Asrc, dA); gll16(Asrc + (size_t)128 * D, dA + 8192); }
        BAR();
        MFMA2(0, 1);
        BAR();
        // ---- P1: B ni2-3 kk0; stage B.kb0 ----
        LOAD_B(b0, 2, 0);
        LOAD_B(b1, 3, 0);
        if (st) { gll16(Bsrc, dB); gll16(Bsrc + (size_t)128 * D, dB + 8192); }
        BAR();
        MFMA2(2, 3);
        if (kt == 31) asm volatile("s_waitcnt vmcnt(0)" ::: "memory");
        else         asm volatile("s_waitcnt vmcnt(4)" ::: "memory");
        BAR();
        // ---- P2: A kk1 (8) + B ni0-1 kk1; stage A.kb1 ----
        LOAD_A(1);
        LOAD_B(b0, 0, 1);
        LOAD_B(b1, 1, 1);
        if (st) { gll16(Asrc + 32, dA + 4096); gll16(Asrc + 32 + (size_t)128 * D, dA + 8192 + 4096); }
        BAR();
        MFMA2(0, 1);
        BAR();
        // ---- P3: B ni2-3 kk1; stage B.kb1 ----
        LOAD_B(b0, 2, 1);
        LOAD_B(b1, 3, 1);
        if (st) { gll16(Bsrc + 32, dB + 4096); gll16(Bsrc + 32 + (size_t)128 * D, dB + 8192 + 4096); }
        BAR();
        MFMA2(2, 3);
        if (kt < 31) asm volatile("s_waitcnt vmcnt(4)" ::: "memory");
        BAR();
    }
#undef LOAD_A
#undef LOAD_B
#undef MFMA2

    // epilogue: rows m0 + wm*128 + mi*16 + lq*4 + r; cols n0 + wn*64 + ni*16 + l16
    if (n0 >= NQKU) {   // V tiles -> vt (B,H,HD,S), rows are contiguous s
#pragma unroll
        for (int mi = 0; mi < 8; ++mi)
#pragma unroll
            for (int ni = 0; ni < 4; ++ni) {
                int c = n0 - NQKU + wn * 64 + ni * 16 + l16;    // 0..2047
                int hh = c >> 7, d = c & 127;
                int row0 = m0 + wm * 128 + mi * 16 + lq * 4;
                int bb = row0 >> 11, s0 = row0 & 2047;
                ushort4 pk = make_ushort4(f2b(acc[mi][ni][0]), f2b(acc[mi][ni][1]),
                                          f2b(acc[mi][ni][2]), f2b(acc[mi][ni][3]));
                *(ushort4*)(vt + (((size_t)(bb * H + hh) * HD + d) * S + s0)) = pk;
            }
    } else {
#pragma unroll
        for (int mi = 0; mi < 8; ++mi)
#pragma unroll
            for (int ni = 0; ni < 4; ++ni)
#pragma unroll
                for (int r = 0; r < 4; ++r) {
                    int row = m0 + wm * 128 + mi * 16 + lq * 4 + r;
                    int col = n0 + wn * 64 + ni * 16 + l16;
                    qku[(size_t)row * NQKU + col] = f2b(acc[mi][ni][r]);
                }
    }
}

// ---------------- GEMM (m97 structure): A(M,K) bf16 @ BT(N,K) bf16, f32 out ----------------
__global__ __launch_bounds__(256)
void gemm_bt_f32(const u16* __restrict__ A, const u16* __restrict__ BT,
                 float* __restrict__ out, int lda, int ldc, int Kk) {
    __shared__ u16 As[128 * 32];
    __shared__ u16 Bs[128 * 32];
    const int tid = threadIdx.x;
    const int lane = tid & 63, w = tid >> 6;
    const int wm = w >> 1, wn = w & 1;
    const int l16 = lane & 15, lq = lane >> 4;
    const int m0 = blockIdx.y * 128, n0 = blockIdx.x * 128;
    const int rs = lane >> 2;
    const int cs = (lane & 3) * 8;
    f32x4 acc[4][4] = {};

    const u16* Ab = A + (size_t)(m0 + w * 32 + rs) * lda + cs;
    const u16* Bb = BT + (size_t)(n0 + w * 32 + rs) * Kk + cs;
    u16* Al = As + w * 32 * 32;
    u16* Bl = Bs + w * 32 * 32;

    for (int k0 = 0; k0 < Kk; k0 += 32) {
        gll16(Ab + k0, Al);
        gll16(Ab + k0 + (size_t)16 * lda, Al + 16 * 32);
        gll16(Bb + k0, Bl);
        gll16(Bb + k0 + (size_t)16 * Kk, Bl + 16 * 32);
        __syncthreads();
        bf16x8 af[4], bfr[4];
#pragma unroll
        for (int mi = 0; mi < 4; mi++)
            af[mi] = *(const bf16x8*)(As + (wm * 64 + mi * 16 + l16) * 32 + lq * 8);
#pragma unroll
        for (int ni = 0; ni < 4; ni++)
            bfr[ni] = *(const bf16x8*)(Bs + (wn * 64 + ni * 16 + l16) * 32 + lq * 8);
#pragma unroll
        for (int mi = 0; mi < 4; mi++)
#pragma unroll
            for (int ni = 0; ni < 4; ni++)
                acc[mi][ni] = __builtin_amdgcn_mfma_f32_16x16x32_bf16(
                    af[mi], bfr[ni], acc[mi][ni], 0, 0, 0);
        __syncthreads();
    }
#pragma unroll
    for (int mi = 0; mi < 4; mi++)
#pragma unroll
        for (int ni = 0; ni < 4; ni++)
#pragma unroll
            for (int r = 0; r < 4; r++) {
                int row = m0 + wm * 64 + mi * 16 + lq * 4 + r;
                int col = n0 + wn * 64 + ni * 16 + l16;
                out[(size_t)row * ldc + col] = acc[mi][ni][r];
            }
}

// ---------------- RoPE(q,k): qku cols -> (B,H,S,HD) ----------------
__global__ __launch_bounds__(256)
void reformat(const u16* __restrict__ qku, const float* __restrict__ fc,
              const float* __restrict__ fs, u16* __restrict__ qr,
              u16* __restrict__ kr) {
    int bh = blockIdx.x;
    int s0 = blockIdx.y * 64;
    int b = bh >> 4, h = bh & 15;
    int tid = threadIdx.x;
#pragma unroll
    for (int i = 0; i < 16; ++i) {
        int p = tid + i * 256;
        int row = p >> 6, pp = p & 63;
        int sgl = s0 + row;
        float c = fc[sgl * 64 + pp], sn = fs[sgl * 64 + pp];
        size_t src = (size_t)(b * S + sgl) * NQKU + h * HD + 2 * pp;
        size_t dst = ((size_t)bh * S + sgl) * HD + 2 * pp;
        {
            uint32_t qv = *(const uint32_t*)(qku + src);
            float r = b2f((u16)(qv & 0xffff)), im = b2f((u16)(qv >> 16));
            uint32_t o = (uint32_t)f2b(r * c - im * sn) |
                         ((uint32_t)f2b(r * sn + im * c) << 16);
            *(uint32_t*)(qr + dst) = o;
        }
        {
            uint32_t kv = *(const uint32_t*)(qku + src + 2048);
            float r = b2f((u16)(kv & 0xffff)), im = b2f((u16)(kv >> 16));
            uint32_t o = (uint32_t)f2b(r * c - im * sn) |
                         ((uint32_t)f2b(r * sn + im * c) << 16);
            *(uint32_t*)(kr + dst) = o;
        }
    }
}

// ---------------- causal silu-attention, QBLK=64, paired tiles (t, 31-t) ----------------
__global__ __launch_bounds__(256)
void hstu_attn(const u16* __restrict__ qr, const u16* __restrict__ kr,
               const u16* __restrict__ vt, float* __restrict__ att) {
    const int bh = blockIdx.y, slot = blockIdx.x;
    const int b = bh >> 4, h = bh & 15;
    const int tid = threadIdx.x, lane = tid & 63, w = tid >> 6;
    const int l16 = lane & 15, lq = lane >> 4;
    const int wm = w >> 1, wn = w & 1;
    constexpr int LDK = 136, LDV = 72, LDS_ = 72;
    __shared__ u16 k_l[64 * LDK];
    __shared__ u16 v_l[128 * LDV];
    __shared__ u16 s_l[64 * LDS_];

    for (int pass = 0; pass < 2; ++pass) {
        const int t = pass ? (31 - slot) : slot;
        const int q0 = t * 64;
        bf16x8 qf[2][4];
#pragma unroll
        for (int mi = 0; mi < 2; mi++)
#pragma unroll
            for (int kk = 0; kk < 4; kk++)
                qf[mi][kk] = *(const bf16x8*)(qr +
                    ((size_t)bh * S + q0 + wm * 32 + mi * 16 + l16) * HD + kk * 32 + lq * 8);
        f32x4 acco[2][4] = {};

        for (int kt = 0; kt <= t; ++kt) {
            const int k0 = kt * 64;
            __syncthreads();
#pragma unroll
            for (int i = 0; i < 4; ++i) {
                int u = tid + i * 256;
                int row = u >> 4, cb = (u & 15) * 8;
                *(int4*)(k_l + row * LDK + cb) =
                    *(const int4*)(kr + ((size_t)bh * S + k0 + row) * HD + cb);
            }
#pragma unroll
            for (int i = 0; i < 4; ++i) {
                int u = tid + i * 256;
                int row = u >> 3, cb = (u & 7) * 8;
                *(int4*)(v_l + row * LDV + cb) =
                    *(const int4*)(vt + ((size_t)bh * HD + row) * S + k0 + cb);
            }
            __syncthreads();
            f32x4 accs[2][2] = {};
            bf16x8 kf[2][4];
#pragma unroll
            for (int ni = 0; ni < 2; ni++)
#pragma unroll
                for (int kk = 0; kk < 4; kk++)
                    kf[ni][kk] = *(const bf16x8*)(k_l + (wn * 32 + ni * 16 + l16) * LDK +
                                                  kk * 32 + lq * 8);
#pragma unroll
            for (int kk = 0; kk < 4; kk++)
#pragma unroll
                for (int mi = 0; mi < 2; mi++)
#pragma unroll
                    for (int ni = 0; ni < 2; ni++)
                        accs[mi][ni] = __builtin_amdgcn_mfma_f32_16x16x32_bf16(
                            qf[mi][kk], kf[ni][kk], accs[mi][ni], 0, 0, 0);
            const bool dg = (kt == t);
#pragma unroll
            for (int mi = 0; mi < 2; mi++)
#pragma unroll
                for (int ni = 0; ni < 2; ni++)
#pragma unroll
                    for (int r = 0; r < 4; r++) {
                        int qrow = wm * 32 + mi * 16 + lq * 4 + r;
                        int krow = wn * 32 + ni * 16 + l16;
                        float vv = accs[mi][ni][r] * SCALE;
                        vv = (!dg || krow <= qrow) ? vv / (1.f + __expf(-vv)) : 0.f;
                        s_l[qrow * LDS_ + krow] = f2b(vv);
                    }
            __syncthreads();
#pragma unroll
            for (int kk = 0; kk < 2; kk++) {
                bf16x8 vf[4];
#pragma unroll
                for (int ni = 0; ni < 4; ni++)
                    vf[ni] = *(const bf16x8*)(v_l + (wn * 64 + ni * 16 + l16) * LDV +
                                              kk * 32 + lq * 8);
#pragma unroll
                for (int mi = 0; mi < 2; mi++) {
                    bf16x8 sf = *(const bf16x8*)(s_l + (wm * 32 + mi * 16 + l16) * LDS_ +
                                                 kk * 32 + lq * 8);
#pragma unroll
                    for (int ni = 0; ni < 4; ni++)
                        acco[mi][ni] = __builtin_amdgcn_mfma_f32_16x16x32_bf16(
                            sf, vf[ni], acco[mi][ni], 0, 0, 0);
                }
            }
        }
#pragma unroll
        for (int mi = 0; mi < 2; mi++)
#pragma unroll
            for (int ni = 0; ni < 4; ni++)
#pragma unroll
                for (int r = 0; r < 4; r++) {
                    int qrow = q0 + wm * 32 + mi * 16 + lq * 4 + r;
                    int d = wn * 64 + ni * 16 + l16;
                    att[(size_t)(b * S + qrow) * ATT_LD + h * HD + d] = acco[mi][ni][r];
                }
    }
}

// ---------------- RMS-norm * norm_w * u (in place over u cols of qku) ----------------
__global__ __launch_bounds__(256)
void rms_mul(const float* __restrict__ att, u16* __restrict__ qku,
             const float* __restrict__ nw) {
    int row = blockIdx.x;
    int tid = threadIdx.x;
    const float* a = att + (size_t)row * ATT_LD + tid * 8;
    float4 v0 = *(const float4*)(a);
    float4 v1 = *(const float4*)(a + 4);
    float ss = v0.x * v0.x + v0.y * v0.y + v0.z * v0.z + v0.w * v0.w +
               v1.x * v1.x + v1.y * v1.y + v1.z * v1.z + v1.w * v1.w;
#pragma unroll
    for (int off = 32; off > 0; off >>= 1) ss += __shfl_down(ss, off, 64);
    __shared__ float red[4];
    int lane = tid & 63, w = tid >> 6;
    if (lane == 0) red[w] = ss;
    __syncthreads();
    float rs = rsqrtf((red[0] + red[1] + red[2] + red[3]) * (1.f / D) + 1e-5f);
    int col = tid * 8;
    u16* up = qku + (size_t)row * NQKU + 4096 + col;
    u16 ut[8];
    *(int4*)ut = *(const int4*)up;
    float f[8] = {v0.x, v0.y, v0.z, v0.w, v1.x, v1.y, v1.z, v1.w};
    u16 o[8];
#pragma unroll
    for (int j = 0; j < 8; j++)
        o[j] = f2b(f[j] * rs * nw[col + j] * b2f(ut[j]));
    *(int4*)up = *(int4*)o;
}

extern "C" void kernel_launch(void* const* d_in, const int* in_sizes, int n_in,
                              void* d_out, int out_size, void* d_ws, size_t ws_size,
                              hipStream_t stream) {
    const float* x  = (const float*)d_in[0];
    const float* fc = (const float*)d_in[1];
    const float* fs = (const float*)d_in[2];
    const float* wq = (const float*)d_in[3];
    const float* wk = (const float*)d_in[4];
    const float* wv = (const float*)d_in[5];
    const float* wu = (const float*)d_in[6];
    const float* wo = (const float*)d_in[7];
    const float* nw = (const float*)d_in[8];
    float* out = (float*)d_out;

    char* ws = (char*)d_ws;
    const size_t WSZ = (size_t)D * D * sizeof(u16);      // 8.39 MB
    // layout (units of WSZ): h_b[0,2) wT[2,7) qku[7,13) vt[13,15) k_r[15,17)
    u16* h_b  = (u16*)(ws);
    u16* wT   = (u16*)(ws + 2 * WSZ);                    // rows: q,k,u,v,o
    u16* qku  = (u16*)(ws + 7 * WSZ);                    // M x 6144
    u16* vt   = (u16*)(ws + 13 * WSZ);                   // (B,H,HD,S)
    u16* k_r  = (u16*)(ws + 15 * WSZ);                   // (B,H,S,HD)
    u16* q_r  = h_b;                                     // overlay (h consumed by GEMM)
    float* att = (float*)qku;                            // overlay q+k cols as f32

    silu_cast<<<M * D / 1024, 256, 0, stream>>>(x, h_b, M * D);
    dim3 wg(32, 32);
    wcast<<<wg, 256, 0, stream>>>(wq, wT + 0 * (size_t)D * D);
    wcast<<<wg, 256, 0, stream>>>(wk, wT + 1 * (size_t)D * D);
    wcast<<<wg, 256, 0, stream>>>(wu, wT + 2 * (size_t)D * D);
    wcast<<<wg, 256, 0, stream>>>(wv, wT + 3 * (size_t)D * D);
    wcast<<<wg, 256, 0, stream>>>(wo, wT + 4 * (size_t)D * D);

    // fused Q,K,U,V GEMM (N=8192): qku linear + V scattered to vt
    gemm_qkuv<<<512, 512, 0, stream>>>(h_b, wT, qku, vt);

    reformat<<<dim3(32, 32), 256, 0, stream>>>(qku, fc, fs, q_r, k_r);
    hstu_attn<<<dim3(16, 32), 256, 0, stream>>>(q_r, k_r, vt, att);
    rms_mul<<<M, 256, 0, stream>>>(att, qku, nw);
    // out = normed(u cols of qku) @ wo^T  (f32 out)
    gemm_bt_f32<<<dim3(D / 128, M / 128), 256, 0, stream>>>(
        qku + 4096, wT + 4 * (size_t)D * D, out, NQKU, D, D);
}

// Round 6
// 361.709 us; speedup vs baseline: 1.8052x; 1.0128x over previous
//
#include <hip/hip_runtime.h>
#include <hip/hip_bf16.h>
#include <cstdint>

typedef __attribute__((ext_vector_type(8))) short bf16x8;
typedef __attribute__((ext_vector_type(4))) float f32x4;
typedef unsigned short u16;

constexpr int B = 2, S = 2048, D = 2048, H = 16, HD = 128;
constexpr int M = B * S;                 // 4096 rows
constexpr int NQKU = 6144;               // q,k,u stored cols
constexpr int ATT_LD = 3072;             // f32 row stride of att overlay (= 6144 u16)
constexpr float SCALE = 0.08838834764831845f;  // 1/sqrt(128)

static __device__ __forceinline__ float b2f(u16 u) {
    union { float f; uint32_t i; } v; v.i = ((uint32_t)u) << 16; return v.f;
}
static __device__ __forceinline__ u16 f2b(float f) {
    union { float f; uint32_t i; } v; v.f = f;
    uint32_t x = v.i;
    return (u16)((x + 0x7FFFu + ((x >> 16) & 1u)) >> 16);
}

__device__ __forceinline__ void gll16(const void* g, void* l) {
    __builtin_amdgcn_global_load_lds(
        (const __attribute__((address_space(1))) uint32_t*)g,
        (__attribute__((address_space(3))) uint32_t*)l, 16, 0, 0);
}

#define BAR() do { asm volatile("" ::: "memory"); __builtin_amdgcn_s_barrier(); \
                   asm volatile("" ::: "memory"); } while (0)

// ---------------- silu(x) f32 -> bf16 ----------------
__global__ __launch_bounds__(256) void silu_cast(const float* __restrict__ x,
                                                 u16* __restrict__ h, int n) {
    int i = (blockIdx.x * 256 + threadIdx.x) * 4;
    if (i >= n) return;
    float4 v = *(const float4*)(x + i);
    ushort4 o;
    o.x = f2b(v.x / (1.f + __expf(-v.x)));
    o.y = f2b(v.y / (1.f + __expf(-v.y)));
    o.z = f2b(v.z / (1.f + __expf(-v.z)));
    o.w = f2b(v.w / (1.f + __expf(-v.w)));
    *(ushort4*)(h + i) = o;
}

// ---------------- weight (K,N) f32 -> wT (N,K) bf16 ----------------
__global__ __launch_bounds__(256) void wcast(const float* __restrict__ w,
                                             u16* __restrict__ wT) {
    __shared__ float t[64][65];
    int tx = threadIdx.x & 63, ty = threadIdx.x >> 6;
    int kb = blockIdx.y * 64, nb = blockIdx.x * 64;
    for (int r = ty; r < 64; r += 4)
        t[r][tx] = w[(size_t)(kb + r) * D + nb + tx];
    __syncthreads();
    for (int r = ty; r < 64; r += 4)
        wT[(size_t)(nb + r) * D + kb + tx] = f2b(t[tx][r]);
}

// ============ fused QKUV GEMM: 256x256 tile, BK=64, 8 waves, 8-phase ============
__global__ __launch_bounds__(512, 2)
void gemm_qkuv(const u16* __restrict__ A, const u16* __restrict__ BT,
               u16* __restrict__ qku, u16* __restrict__ vt) {
    __shared__ u16 lds[65536];  // 128 KiB: A0|B0|A1|B1 (32KB each)
    const int tid = threadIdx.x;
    const int lane = tid & 63, wid = tid >> 6;
    const int wm = wid >> 2, wn = wid & 3;       // 2 x 4 waves
    const int l16 = lane & 15, lq = lane >> 4;

    const int orig = blockIdx.x;
    const int swz = (orig & 7) * 64 + (orig >> 3);
    const int mt = swz & 15, nt = swz >> 4;      // 16 m-tiles x 32 n-tiles
    const int m0 = mt * 256, n0 = nt * 256;

    const int srow = tid >> 2;                                   // 0..127
    const int ce = ((tid & 3) * 8) ^ (((tid >> 5) & 1) << 4);    // elems
    const int rdx = (lq * 16) ^ (((l16 >> 3) & 1) << 5);         // bytes

    const u16* As0 = A + (size_t)(m0 + srow) * D + ce;
    const u16* Bs0 = BT + (size_t)(n0 + srow) * D + ce;

    {
        u16* dA = lds + wid * 512;
        u16* dB = lds + 16384 + wid * 512;
        gll16(As0,                    dA);
        gll16(As0 + (size_t)128 * D,  dA + 8192);
        gll16(Bs0,                    dB);
        gll16(Bs0 + (size_t)128 * D,  dB + 8192);
        gll16(As0 + 32,                    dA + 4096);
        gll16(As0 + 32 + (size_t)128 * D,  dA + 8192 + 4096);
        gll16(Bs0 + 32,                    dB + 4096);
        gll16(Bs0 + 32 + (size_t)128 * D,  dB + 8192 + 4096);
    }
    asm volatile("s_waitcnt vmcnt(4)" ::: "memory");
    BAR();

    f32x4 acc[8][4] = {};
    bf16x8 a[8];
    const int rbB = (wn & 1) * 4096;  // byte row-base within B half

#define LOAD_A(kk)                                                            \
    _Pragma("unroll") for (int mi = 0; mi < 8; ++mi)                          \
        a[mi] = *(const bf16x8*)(Abase + (kk) * 8192 +                        \
                                 (mi * 16 + l16) * 64 + rdx);
#define LOAD_B(dst, nia, kk)                                                  \
    dst = *(const bf16x8*)(Bbase + (kk) * 8192 + rbB +                        \
                           ((nia) * 16 + l16) * 64 + rdx);
#define MFMA2(n0i, n1i)                                                       \
    __builtin_amdgcn_s_setprio(1);                                            \
    _Pragma("unroll") for (int mi = 0; mi < 8; ++mi) {                        \
        acc[mi][n0i] = __builtin_amdgcn_mfma_f32_16x16x32_bf16(a[mi], b0,     \
                            acc[mi][n0i], 0, 0, 0);                           \
        acc[mi][n1i] = __builtin_amdgcn_mfma_f32_16x16x32_bf16(a[mi], b1,     \
                            acc[mi][n1i], 0, 0, 0);                           \
    }                                                                          \
    __builtin_amdgcn_s_setprio(0);

    for (int kt = 0; kt < 32; ++kt) {
        const int buf = kt & 1;
        const char* Abase = (const char*)lds + buf * 65536 + wm * 16384;
        const char* Bbase = (const char*)lds + 32768 + buf * 65536 + (wn >> 1) * 16384;
        const bool st = (kt + 1) < 32;
        const u16* Asrc = As0 + (kt + 1) * 64;
        const u16* Bsrc = Bs0 + (kt + 1) * 64;
        u16* dA = lds + (buf ^ 1) * 32768 + wid * 512;
        u16* dB = dA + 16384;
        bf16x8 b0, b1;

        LOAD_A(0);
        LOAD_B(b0, 0, 0);
        LOAD_B(b1, 1, 0);
        if (st) { gll16(Asrc, dA); gll16(Asrc + (size_t)128 * D, dA + 8192); }
        BAR();
        MFMA2(0, 1);
        BAR();
        LOAD_B(b0, 2, 0);
        LOAD_B(b1, 3, 0);
        if (st) { gll16(Bsrc, dB); gll16(Bsrc + (size_t)128 * D, dB + 8192); }
        BAR();
        MFMA2(2, 3);
        if (kt == 31) asm volatile("s_waitcnt vmcnt(0)" ::: "memory");
        else         asm volatile("s_waitcnt vmcnt(4)" ::: "memory");
        BAR();
        LOAD_A(1);
        LOAD_B(b0, 0, 1);
        LOAD_B(b1, 1, 1);
        if (st) { gll16(Asrc + 32, dA + 4096); gll16(Asrc + 32 + (size_t)128 * D, dA + 8192 + 4096); }
        BAR();
        MFMA2(0, 1);
        BAR();
        LOAD_B(b0, 2, 1);
        LOAD_B(b1, 3, 1);
        if (st) { gll16(Bsrc + 32, dB + 4096); gll16(Bsrc + 32 + (size_t)128 * D, dB + 8192 + 4096); }
        BAR();
        MFMA2(2, 3);
        if (kt < 31) asm volatile("s_waitcnt vmcnt(4)" ::: "memory");
        BAR();
    }
#undef LOAD_A
#undef LOAD_B
#undef MFMA2

    if (n0 >= NQKU) {   // V tiles -> vt (B,H,HD,S)
#pragma unroll
        for (int mi = 0; mi < 8; ++mi)
#pragma unroll
            for (int ni = 0; ni < 4; ++ni) {
                int c = n0 - NQKU + wn * 64 + ni * 16 + l16;
                int hh = c >> 7, d = c & 127;
                int row0 = m0 + wm * 128 + mi * 16 + lq * 4;
                int bb = row0 >> 11, s0 = row0 & 2047;
                ushort4 pk = make_ushort4(f2b(acc[mi][ni][0]), f2b(acc[mi][ni][1]),
                                          f2b(acc[mi][ni][2]), f2b(acc[mi][ni][3]));
                *(ushort4*)(vt + (((size_t)(bb * H + hh) * HD + d) * S + s0)) = pk;
            }
    } else {
#pragma unroll
        for (int mi = 0; mi < 8; ++mi)
#pragma unroll
            for (int ni = 0; ni < 4; ++ni)
#pragma unroll
                for (int r = 0; r < 4; ++r) {
                    int row = m0 + wm * 128 + mi * 16 + lq * 4 + r;
                    int col = n0 + wn * 64 + ni * 16 + l16;
                    qku[(size_t)row * NQKU + col] = f2b(acc[mi][ni][r]);
                }
    }
}

// ---------------- GEMM (m97 structure): f32 out ----------------
__global__ __launch_bounds__(256)
void gemm_bt_f32(const u16* __restrict__ A, const u16* __restrict__ BT,
                 float* __restrict__ out, int lda, int ldc, int Kk) {
    __shared__ u16 As[128 * 32];
    __shared__ u16 Bs[128 * 32];
    const int tid = threadIdx.x;
    const int lane = tid & 63, w = tid >> 6;
    const int wm = w >> 1, wn = w & 1;
    const int l16 = lane & 15, lq = lane >> 4;
    const int m0 = blockIdx.y * 128, n0 = blockIdx.x * 128;
    const int rs = lane >> 2;
    const int cs = (lane & 3) * 8;
    f32x4 acc[4][4] = {};

    const u16* Ab = A + (size_t)(m0 + w * 32 + rs) * lda + cs;
    const u16* Bb = BT + (size_t)(n0 + w * 32 + rs) * Kk + cs;
    u16* Al = As + w * 32 * 32;
    u16* Bl = Bs + w * 32 * 32;

    for (int k0 = 0; k0 < Kk; k0 += 32) {
        gll16(Ab + k0, Al);
        gll16(Ab + k0 + (size_t)16 * lda, Al + 16 * 32);
        gll16(Bb + k0, Bl);
        gll16(Bb + k0 + (size_t)16 * Kk, Bl + 16 * 32);
        __syncthreads();
        bf16x8 af[4], bfr[4];
#pragma unroll
        for (int mi = 0; mi < 4; mi++)
            af[mi] = *(const bf16x8*)(As + (wm * 64 + mi * 16 + l16) * 32 + lq * 8);
#pragma unroll
        for (int ni = 0; ni < 4; ni++)
            bfr[ni] = *(const bf16x8*)(Bs + (wn * 64 + ni * 16 + l16) * 32 + lq * 8);
#pragma unroll
        for (int mi = 0; mi < 4; mi++)
#pragma unroll
            for (int ni = 0; ni < 4; ni++)
                acc[mi][ni] = __builtin_amdgcn_mfma_f32_16x16x32_bf16(
                    af[mi], bfr[ni], acc[mi][ni], 0, 0, 0);
        __syncthreads();
    }
#pragma unroll
    for (int mi = 0; mi < 4; mi++)
#pragma unroll
        for (int ni = 0; ni < 4; ni++)
#pragma unroll
            for (int r = 0; r < 4; r++) {
                int row = m0 + wm * 64 + mi * 16 + lq * 4 + r;
                int col = n0 + wn * 64 + ni * 16 + l16;
                out[(size_t)row * ldc + col] = acc[mi][ni][r];
            }
}

// ---------------- RoPE(q,k): qku cols -> (B,H,S,HD) ----------------
__global__ __launch_bounds__(256)
void reformat(const u16* __restrict__ qku, const float* __restrict__ fc,
              const float* __restrict__ fs, u16* __restrict__ qr,
              u16* __restrict__ kr) {
    int bh = blockIdx.x;
    int s0 = blockIdx.y * 64;
    int b = bh >> 4, h = bh & 15;
    int tid = threadIdx.x;
#pragma unroll
    for (int i = 0; i < 16; ++i) {
        int p = tid + i * 256;
        int row = p >> 6, pp = p & 63;
        int sgl = s0 + row;
        float c = fc[sgl * 64 + pp], sn = fs[sgl * 64 + pp];
        size_t src = (size_t)(b * S + sgl) * NQKU + h * HD + 2 * pp;
        size_t dst = ((size_t)bh * S + sgl) * HD + 2 * pp;
        {
            uint32_t qv = *(const uint32_t*)(qku + src);
            float r = b2f((u16)(qv & 0xffff)), im = b2f((u16)(qv >> 16));
            uint32_t o = (uint32_t)f2b(r * c - im * sn) |
                         ((uint32_t)f2b(r * sn + im * c) << 16);
            *(uint32_t*)(qr + dst) = o;
        }
        {
            uint32_t kv = *(const uint32_t*)(qku + src + 2048);
            float r = b2f((u16)(kv & 0xffff)), im = b2f((u16)(kv >> 16));
            uint32_t o = (uint32_t)f2b(r * c - im * sn) |
                         ((uint32_t)f2b(r * sn + im * c) << 16);
            *(uint32_t*)(kr + dst) = o;
        }
    }
}

// ======== causal silu-attention: 8 waves, QBLK=128, KBLK=128, paired (t,15-t) ========
// q,k: (B,H,S,HD) rope'd; v: vt (B,H,HD,S). K/V staged swizzled via global_load_lds,
// staging overlapped with the opposite compute phase (counted vmcnt).
__global__ __launch_bounds__(512, 2)
void hstu_attn(const u16* __restrict__ qr, const u16* __restrict__ kr,
               const u16* __restrict__ vt, float* __restrict__ att) {
    __shared__ u16 k_l[16384];       // [128 k][128 d], XOR-swizzled units
    __shared__ u16 v_l[16384];       // [128 d][128 s], XOR-swizzled units
    __shared__ u16 s_l[8 * 16 * 136];// per-wave [16 q][136]
    const int bh = blockIdx.x & 31, slot = blockIdx.x >> 5;   // bh fast: L2 reuse of K/V within XCD? (bh in blockIdx.x&31)
    const int b = bh >> 4, h = bh & 15;
    const int tid = threadIdx.x, lane = tid & 63, w = tid >> 6;
    const int l16 = lane & 15, lq = lane >> 4;
    u16* s_w = s_l + w * 16 * 136;

    const u16* kb = kr + (size_t)bh * S * HD;
    const u16* vb = vt + (size_t)bh * HD * S;

    // staging geometry: round r_: i = tid + r_*512; row = i>>4; unit = (i&15)^(row&7)
    const int irow0 = tid >> 4, iu0 = tid & 15;

#define STAGE_K(k0_)                                                          \
    _Pragma("unroll") for (int r_ = 0; r_ < 4; ++r_) {                        \
        int row_ = irow0 + r_ * 32;                                           \
        int uc_ = iu0 ^ (row_ & 7);                                           \
        gll16(kb + (size_t)(k0_ + row_) * HD + uc_ * 8,                       \
              k_l + ((w * 64 + r_ * 512) << 3));                              \
    }
#define STAGE_V(k0_)                                                          \
    _Pragma("unroll") for (int r_ = 0; r_ < 4; ++r_) {                        \
        int row_ = irow0 + r_ * 32;                                           \
        int uc_ = iu0 ^ (row_ & 7);                                           \
        gll16(vb + (size_t)row_ * S + (k0_) + uc_ * 8,                        \
              v_l + ((w * 64 + r_ * 512) << 3));                              \
    }

    for (int pass = 0; pass < 2; ++pass) {
        const int t = pass ? (15 - slot) : slot;
        const int q0 = t * 128;
        const int qg0 = q0 + w * 16;

        bf16x8 qf[4];
#pragma unroll
        for (int kk = 0; kk < 4; ++kk)
            qf[kk] = *(const bf16x8*)(qr + ((size_t)bh * S + qg0 + l16) * HD +
                                      kk * 32 + lq * 8);
        f32x4 acco[8] = {};

        STAGE_K(0);
        STAGE_V(0);
        asm volatile("s_waitcnt vmcnt(0)" ::: "memory");
        BAR();

        for (int kt = 0; kt <= t; ++kt) {
            const int k0 = kt * 128;
            const bool st = kt < t;
            // ---- QK^T: 16q x 128k ----
            f32x4 accs[8] = {};
            __builtin_amdgcn_s_setprio(1);
#pragma unroll
            for (int kk = 0; kk < 4; ++kk)
#pragma unroll
                for (int ni = 0; ni < 8; ++ni) {
                    int row = ni * 16 + l16;
                    bf16x8 kf = *(const bf16x8*)(k_l + row * 128 +
                                ((kk * 32 + lq * 8) ^ ((row & 7) << 3)));
                    accs[ni] = __builtin_amdgcn_mfma_f32_16x16x32_bf16(
                        qf[kk], kf, accs[ni], 0, 0, 0);
                }
            __builtin_amdgcn_s_setprio(0);
            // softmax (silu) -> s_w (wave-private)
            const bool dg = (kt == t);
#pragma unroll
            for (int ni = 0; ni < 8; ++ni)
#pragma unroll
                for (int r = 0; r < 4; ++r) {
                    int qrow = lq * 4 + r;
                    int krow = ni * 16 + l16;
                    float vv = accs[ni][r] * SCALE;
                    vv = (!dg || (k0 + krow <= qg0 + qrow))
                             ? vv / (1.f + __expf(-vv)) : 0.f;
                    s_w[qrow * 136 + krow] = f2b(vv);
                }
            BAR();                       // all waves done reading k_l
            if (st) STAGE_K(k0 + 128);   // overlaps PV
            if (st) asm volatile("s_waitcnt vmcnt(4)" ::: "memory");  // V(kt) done
            else    asm volatile("s_waitcnt vmcnt(0)" ::: "memory");
            BAR();                       // V(kt) visible to all
            // ---- PV: 16q x 128d over 128 s ----
            __builtin_amdgcn_s_setprio(1);
#pragma unroll
            for (int kk = 0; kk < 4; ++kk) {
                bf16x8 sf = *(const bf16x8*)(s_w + l16 * 136 + kk * 32 + lq * 8);
#pragma unroll
                for (int ni = 0; ni < 8; ++ni) {
                    int row = ni * 16 + l16;
                    bf16x8 vf = *(const bf16x8*)(v_l + row * 128 +
                                ((kk * 32 + lq * 8) ^ ((row & 7) << 3)));
                    acco[ni] = __builtin_amdgcn_mfma_f32_16x16x32_bf16(
                        sf, vf, acco[ni], 0, 0, 0);
                }
            }
            __builtin_amdgcn_s_setprio(0);
            BAR();                       // all waves done reading v_l
            if (st) {
                STAGE_V(k0 + 128);
                asm volatile("s_waitcnt vmcnt(4)" ::: "memory");  // K(kt+1) done
            }
            BAR();                       // k_l(kt+1) visible
        }
        // epilogue: att rows (f32, stride ATT_LD)
#pragma unroll
        for (int ni = 0; ni < 8; ++ni)
#pragma unroll
            for (int r = 0; r < 4; ++r)
                att[(size_t)(b * S + qg0 + lq * 4 + r) * ATT_LD +
                    h * HD + ni * 16 + l16] = acco[ni][r];
    }
#undef STAGE_K
#undef STAGE_V
}

// ---------------- RMS-norm * norm_w * u (in place over u cols of qku) ----------------
__global__ __launch_bounds__(256)
void rms_mul(const float* __restrict__ att, u16* __restrict__ qku,
             const float* __restrict__ nw) {
    int row = blockIdx.x;
    int tid = threadIdx.x;
    const float* a = att + (size_t)row * ATT_LD + tid * 8;
    float4 v0 = *(const float4*)(a);
    float4 v1 = *(const float4*)(a + 4);
    float ss = v0.x * v0.x + v0.y * v0.y + v0.z * v0.z + v0.w * v0.w +
               v1.x * v1.x + v1.y * v1.y + v1.z * v1.z + v1.w * v1.w;
#pragma unroll
    for (int off = 32; off > 0; off >>= 1) ss += __shfl_down(ss, off, 64);
    __shared__ float red[4];
    int lane = tid & 63, w = tid >> 6;
    if (lane == 0) red[w] = ss;
    __syncthreads();
    float rs = rsqrtf((red[0] + red[1] + red[2] + red[3]) * (1.f / D) + 1e-5f);
    int col = tid * 8;
    u16* up = qku + (size_t)row * NQKU + 4096 + col;
    u16 ut[8];
    *(int4*)ut = *(const int4*)up;
    float f[8] = {v0.x, v0.y, v0.z, v0.w, v1.x, v1.y, v1.z, v1.w};
    u16 o[8];
#pragma unroll
    for (int j = 0; j < 8; j++)
        o[j] = f2b(f[j] * rs * nw[col + j] * b2f(ut[j]));
    *(int4*)up = *(int4*)o;
}

extern "C" void kernel_launch(void* const* d_in, const int* in_sizes, int n_in,
                              void* d_out, int out_size, void* d_ws, size_t ws_size,
                              hipStream_t stream) {
    const float* x  = (const float*)d_in[0];
    const float* fc = (const float*)d_in[1];
    const float* fs = (const float*)d_in[2];
    const float* wq = (const float*)d_in[3];
    const float* wk = (const float*)d_in[4];
    const float* wv = (const float*)d_in[5];
    const float* wu = (const float*)d_in[6];
    const float* wo = (const float*)d_in[7];
    const float* nw = (const float*)d_in[8];
    float* out = (float*)d_out;

    char* ws = (char*)d_ws;
    const size_t WSZ = (size_t)D * D * sizeof(u16);      // 8.39 MB
    u16* h_b  = (u16*)(ws);
    u16* wT   = (u16*)(ws + 2 * WSZ);                    // rows: q,k,u,v,o
    u16* qku  = (u16*)(ws + 7 * WSZ);                    // M x 6144
    u16* vt   = (u16*)(ws + 13 * WSZ);                   // (B,H,HD,S)
    u16* k_r  = (u16*)(ws + 15 * WSZ);                   // (B,H,S,HD)
    u16* q_r  = h_b;                                     // overlay (h consumed by GEMM)
    float* att = (float*)qku;                            // overlay q+k cols as f32

    silu_cast<<<M * D / 1024, 256, 0, stream>>>(x, h_b, M * D);
    dim3 wg(32, 32);
    wcast<<<wg, 256, 0, stream>>>(wq, wT + 0 * (size_t)D * D);
    wcast<<<wg, 256, 0, stream>>>(wk, wT + 1 * (size_t)D * D);
    wcast<<<wg, 256, 0, stream>>>(wu, wT + 2 * (size_t)D * D);
    wcast<<<wg, 256, 0, stream>>>(wv, wT + 3 * (size_t)D * D);
    wcast<<<wg, 256, 0, stream>>>(wo, wT + 4 * (size_t)D * D);

    gemm_qkuv<<<512, 512, 0, stream>>>(h_b, wT, qku, vt);

    reformat<<<dim3(32, 32), 256, 0, stream>>>(qku, fc, fs, q_r, k_r);
    hstu_attn<<<256, 512, 0, stream>>>(q_r, k_r, vt, att);
    rms_mul<<<M, 256, 0, stream>>>(att, qku, nw);
    gemm_bt_f32<<<dim3(D / 128, M / 128), 256, 0, stream>>>(
        qku + 4096, wT + 4 * (size_t)D * D, out, NQKU, D, D);
}

// Round 7
// 342.537 us; speedup vs baseline: 1.9062x; 1.0560x over previous
//
#include <hip/hip_runtime.h>
#include <hip/hip_bf16.h>
#include <cstdint>

typedef __attribute__((ext_vector_type(8))) short bf16x8;
typedef __attribute__((ext_vector_type(4))) float f32x4;
typedef unsigned short u16;

constexpr int B = 2, S = 2048, D = 2048, H = 16, HD = 128;
constexpr int M = B * S;                 // 4096 rows
constexpr int NQKU = 6144;               // q,k,u stored cols
constexpr int ATT_LD = 3072;             // f32 row stride of att overlay (= 6144 u16)
constexpr float SCALE = 0.08838834764831845f;  // 1/sqrt(128)

static __device__ __forceinline__ float b2f(u16 u) {
    union { float f; uint32_t i; } v; v.i = ((uint32_t)u) << 16; return v.f;
}
static __device__ __forceinline__ u16 f2b(float f) {
    union { float f; uint32_t i; } v; v.f = f;
    uint32_t x = v.i;
    return (u16)((x + 0x7FFFu + ((x >> 16) & 1u)) >> 16);
}

__device__ __forceinline__ void gll16(const void* g, void* l) {
    __builtin_amdgcn_global_load_lds(
        (const __attribute__((address_space(1))) uint32_t*)g,
        (__attribute__((address_space(3))) uint32_t*)l, 16, 0, 0);
}

#define BAR() do { asm volatile("" ::: "memory"); __builtin_amdgcn_s_barrier(); \
                   asm volatile("" ::: "memory"); } while (0)

// ---------------- silu(x) f32 -> bf16 ----------------
__global__ __launch_bounds__(256) void silu_cast(const float* __restrict__ x,
                                                 u16* __restrict__ h, int n) {
    int i = (blockIdx.x * 256 + threadIdx.x) * 4;
    if (i >= n) return;
    float4 v = *(const float4*)(x + i);
    ushort4 o;
    o.x = f2b(v.x / (1.f + __expf(-v.x)));
    o.y = f2b(v.y / (1.f + __expf(-v.y)));
    o.z = f2b(v.z / (1.f + __expf(-v.z)));
    o.w = f2b(v.w / (1.f + __expf(-v.w)));
    *(ushort4*)(h + i) = o;
}

// ---------------- weight (K,N) f32 -> wT (N,K) bf16 ----------------
__global__ __launch_bounds__(256) void wcast(const float* __restrict__ w,
                                             u16* __restrict__ wT) {
    __shared__ float t[64][65];
    int tx = threadIdx.x & 63, ty = threadIdx.x >> 6;
    int kb = blockIdx.y * 64, nb = blockIdx.x * 64;
    for (int r = ty; r < 64; r += 4)
        t[r][tx] = w[(size_t)(kb + r) * D + nb + tx];
    __syncthreads();
    for (int r = ty; r < 64; r += 4)
        wT[(size_t)(nb + r) * D + kb + tx] = f2b(t[tx][r]);
}

// ============ fused QKUV GEMM: 256x256 tile, BK=64, 8 waves, 8-phase ============
__global__ __launch_bounds__(512, 2)
void gemm_qkuv(const u16* __restrict__ A, const u16* __restrict__ BT,
               u16* __restrict__ qku, u16* __restrict__ vt) {
    __shared__ u16 lds[65536];  // 128 KiB: A0|B0|A1|B1 (32KB each)
    const int tid = threadIdx.x;
    const int lane = tid & 63, wid = tid >> 6;
    const int wm = wid >> 2, wn = wid & 3;       // 2 x 4 waves
    const int l16 = lane & 15, lq = lane >> 4;

    const int orig = blockIdx.x;
    const int swz = (orig & 7) * 64 + (orig >> 3);
    const int mt = swz & 15, nt = swz >> 4;      // 16 m-tiles x 32 n-tiles
    const int m0 = mt * 256, n0 = nt * 256;

    const int srow = tid >> 2;                                   // 0..127
    const int ce = ((tid & 3) * 8) ^ (((tid >> 5) & 1) << 4);    // elems
    const int rdx = (lq * 16) ^ (((l16 >> 3) & 1) << 5);         // bytes

    const u16* As0 = A + (size_t)(m0 + srow) * D + ce;
    const u16* Bs0 = BT + (size_t)(n0 + srow) * D + ce;

    {
        u16* dA = lds + wid * 512;
        u16* dB = lds + 16384 + wid * 512;
        gll16(As0,                    dA);
        gll16(As0 + (size_t)128 * D,  dA + 8192);
        gll16(Bs0,                    dB);
        gll16(Bs0 + (size_t)128 * D,  dB + 8192);
        gll16(As0 + 32,                    dA + 4096);
        gll16(As0 + 32 + (size_t)128 * D,  dA + 8192 + 4096);
        gll16(Bs0 + 32,                    dB + 4096);
        gll16(Bs0 + 32 + (size_t)128 * D,  dB + 8192 + 4096);
    }
    asm volatile("s_waitcnt vmcnt(4)" ::: "memory");
    BAR();

    f32x4 acc[8][4] = {};
    bf16x8 a[8];
    const int rbB = (wn & 1) * 4096;  // byte row-base within B half

#define LOAD_A(kk)                                                            \
    _Pragma("unroll") for (int mi = 0; mi < 8; ++mi)                          \
        a[mi] = *(const bf16x8*)(Abase + (kk) * 8192 +                        \
                                 (mi * 16 + l16) * 64 + rdx);
#define LOAD_B(dst, nia, kk)                                                  \
    dst = *(const bf16x8*)(Bbase + (kk) * 8192 + rbB +                        \
                           ((nia) * 16 + l16) * 64 + rdx);
#define MFMA2(n0i, n1i)                                                       \
    __builtin_amdgcn_s_setprio(1);                                            \
    _Pragma("unroll") for (int mi = 0; mi < 8; ++mi) {                        \
        acc[mi][n0i] = __builtin_amdgcn_mfma_f32_16x16x32_bf16(a[mi], b0,     \
                            acc[mi][n0i], 0, 0, 0);                           \
        acc[mi][n1i] = __builtin_amdgcn_mfma_f32_16x16x32_bf16(a[mi], b1,     \
                            acc[mi][n1i], 0, 0, 0);                           \
    }                                                                          \
    __builtin_amdgcn_s_setprio(0);

    for (int kt = 0; kt < 32; ++kt) {
        const int buf = kt & 1;
        const char* Abase = (const char*)lds + buf * 65536 + wm * 16384;
        const char* Bbase = (const char*)lds + 32768 + buf * 65536 + (wn >> 1) * 16384;
        const bool st = (kt + 1) < 32;
        const u16* Asrc = As0 + (kt + 1) * 64;
        const u16* Bsrc = Bs0 + (kt + 1) * 64;
        u16* dA = lds + (buf ^ 1) * 32768 + wid * 512;
        u16* dB = dA + 16384;
        bf16x8 b0, b1;

        LOAD_A(0);
        LOAD_B(b0, 0, 0);
        LOAD_B(b1, 1, 0);
        if (st) { gll16(Asrc, dA); gll16(Asrc + (size_t)128 * D, dA + 8192); }
        BAR();
        MFMA2(0, 1);
        BAR();
        LOAD_B(b0, 2, 0);
        LOAD_B(b1, 3, 0);
        if (st) { gll16(Bsrc, dB); gll16(Bsrc + (size_t)128 * D, dB + 8192); }
        BAR();
        MFMA2(2, 3);
        if (kt == 31) asm volatile("s_waitcnt vmcnt(0)" ::: "memory");
        else         asm volatile("s_waitcnt vmcnt(4)" ::: "memory");
        BAR();
        LOAD_A(1);
        LOAD_B(b0, 0, 1);
        LOAD_B(b1, 1, 1);
        if (st) { gll16(Asrc + 32, dA + 4096); gll16(Asrc + 32 + (size_t)128 * D, dA + 8192 + 4096); }
        BAR();
        MFMA2(0, 1);
        BAR();
        LOAD_B(b0, 2, 1);
        LOAD_B(b1, 3, 1);
        if (st) { gll16(Bsrc + 32, dB + 4096); gll16(Bsrc + 32 + (size_t)128 * D, dB + 8192 + 4096); }
        BAR();
        MFMA2(2, 3);
        if (kt < 31) asm volatile("s_waitcnt vmcnt(4)" ::: "memory");
        BAR();
    }
#undef LOAD_A
#undef LOAD_B
#undef MFMA2

    if (n0 >= NQKU) {   // V tiles -> vt (B,H,HD,S)
#pragma unroll
        for (int mi = 0; mi < 8; ++mi)
#pragma unroll
            for (int ni = 0; ni < 4; ++ni) {
                int c = n0 - NQKU + wn * 64 + ni * 16 + l16;
                int hh = c >> 7, d = c & 127;
                int row0 = m0 + wm * 128 + mi * 16 + lq * 4;
                int bb = row0 >> 11, s0 = row0 & 2047;
                ushort4 pk = make_ushort4(f2b(acc[mi][ni][0]), f2b(acc[mi][ni][1]),
                                          f2b(acc[mi][ni][2]), f2b(acc[mi][ni][3]));
                *(ushort4*)(vt + (((size_t)(bb * H + hh) * HD + d) * S + s0)) = pk;
            }
    } else {
#pragma unroll
        for (int mi = 0; mi < 8; ++mi)
#pragma unroll
            for (int ni = 0; ni < 4; ++ni)
#pragma unroll
                for (int r = 0; r < 4; ++r) {
                    int row = m0 + wm * 128 + mi * 16 + lq * 4 + r;
                    int col = n0 + wn * 64 + ni * 16 + l16;
                    qku[(size_t)row * NQKU + col] = f2b(acc[mi][ni][r]);
                }
    }
}

// ---------------- GEMM (m97 structure): f32 out ----------------
__global__ __launch_bounds__(256)
void gemm_bt_f32(const u16* __restrict__ A, const u16* __restrict__ BT,
                 float* __restrict__ out, int lda, int ldc, int Kk) {
    __shared__ u16 As[128 * 32];
    __shared__ u16 Bs[128 * 32];
    const int tid = threadIdx.x;
    const int lane = tid & 63, w = tid >> 6;
    const int wm = w >> 1, wn = w & 1;
    const int l16 = lane & 15, lq = lane >> 4;
    const int m0 = blockIdx.y * 128, n0 = blockIdx.x * 128;
    const int rs = lane >> 2;
    const int cs = (lane & 3) * 8;
    f32x4 acc[4][4] = {};

    const u16* Ab = A + (size_t)(m0 + w * 32 + rs) * lda + cs;
    const u16* Bb = BT + (size_t)(n0 + w * 32 + rs) * Kk + cs;
    u16* Al = As + w * 32 * 32;
    u16* Bl = Bs + w * 32 * 32;

    for (int k0 = 0; k0 < Kk; k0 += 32) {
        gll16(Ab + k0, Al);
        gll16(Ab + k0 + (size_t)16 * lda, Al + 16 * 32);
        gll16(Bb + k0, Bl);
        gll16(Bb + k0 + (size_t)16 * Kk, Bl + 16 * 32);
        __syncthreads();
        bf16x8 af[4], bfr[4];
#pragma unroll
        for (int mi = 0; mi < 4; mi++)
            af[mi] = *(const bf16x8*)(As + (wm * 64 + mi * 16 + l16) * 32 + lq * 8);
#pragma unroll
        for (int ni = 0; ni < 4; ni++)
            bfr[ni] = *(const bf16x8*)(Bs + (wn * 64 + ni * 16 + l16) * 32 + lq * 8);
#pragma unroll
        for (int mi = 0; mi < 4; mi++)
#pragma unroll
            for (int ni = 0; ni < 4; ni++)
                acc[mi][ni] = __builtin_amdgcn_mfma_f32_16x16x32_bf16(
                    af[mi], bfr[ni], acc[mi][ni], 0, 0, 0);
        __syncthreads();
    }
#pragma unroll
    for (int mi = 0; mi < 4; mi++)
#pragma unroll
        for (int ni = 0; ni < 4; ni++)
#pragma unroll
            for (int r = 0; r < 4; r++) {
                int row = m0 + wm * 64 + mi * 16 + lq * 4 + r;
                int col = n0 + wn * 64 + ni * 16 + l16;
                out[(size_t)row * ldc + col] = acc[mi][ni][r];
            }
}

// ---------------- RoPE(q,k): qku cols -> (B,H,S,HD) ----------------
__global__ __launch_bounds__(256)
void reformat(const u16* __restrict__ qku, const float* __restrict__ fc,
              const float* __restrict__ fs, u16* __restrict__ qr,
              u16* __restrict__ kr) {
    int bh = blockIdx.x;
    int s0 = blockIdx.y * 64;
    int b = bh >> 4, h = bh & 15;
    int tid = threadIdx.x;
#pragma unroll
    for (int i = 0; i < 16; ++i) {
        int p = tid + i * 256;
        int row = p >> 6, pp = p & 63;
        int sgl = s0 + row;
        float c = fc[sgl * 64 + pp], sn = fs[sgl * 64 + pp];
        size_t src = (size_t)(b * S + sgl) * NQKU + h * HD + 2 * pp;
        size_t dst = ((size_t)bh * S + sgl) * HD + 2 * pp;
        {
            uint32_t qv = *(const uint32_t*)(qku + src);
            float r = b2f((u16)(qv & 0xffff)), im = b2f((u16)(qv >> 16));
            uint32_t o = (uint32_t)f2b(r * c - im * sn) |
                         ((uint32_t)f2b(r * sn + im * c) << 16);
            *(uint32_t*)(qr + dst) = o;
        }
        {
            uint32_t kv = *(const uint32_t*)(qku + src + 2048);
            float r = b2f((u16)(kv & 0xffff)), im = b2f((u16)(kv >> 16));
            uint32_t o = (uint32_t)f2b(r * c - im * sn) |
                         ((uint32_t)f2b(r * sn + im * c) << 16);
            *(uint32_t*)(kr + dst) = o;
        }
    }
}

// ======== causal silu-attention: 8 waves (2 q-bands x 4 k/d-slices), QBLK=KBLK=128 ========
// Wave (wq, wk4) owns 64 q-rows and a 32-col slice of k (QK) / d (PV).
// K/V staged via global_load_lds (XOR-swizzled source), counted vmcnt overlap.
__global__ __launch_bounds__(512, 2)
void hstu_attn(const u16* __restrict__ qr, const u16* __restrict__ kr,
               const u16* __restrict__ vt, float* __restrict__ att) {
    __shared__ u16 k_l[16384];       // [128 k][128 d], XOR-swizzled units
    __shared__ u16 v_l[16384];       // [128 d][128 s], XOR-swizzled units
    __shared__ u16 s_l[128 * 136];   // [128 q][128 k] + 8 pad
    const int bh = blockIdx.x & 31, slot = blockIdx.x >> 5;
    const int b = bh >> 4, h = bh & 15;
    const int tid = threadIdx.x, lane = tid & 63, w = tid >> 6;
    const int l16 = lane & 15, lq = lane >> 4;
    const int wq = w >> 2, wk4 = w & 3;      // wq: 64 q rows; wk4: 32 cols

    const u16* kb = kr + (size_t)bh * S * HD;
    const u16* vb = vt + (size_t)bh * HD * S;
    const int irow0 = tid >> 4, iu0 = tid & 15;

#define STAGE_K(k0_)                                                          \
    _Pragma("unroll") for (int r_ = 0; r_ < 4; ++r_) {                        \
        int row_ = irow0 + r_ * 32;                                           \
        int uc_ = iu0 ^ (row_ & 7);                                           \
        gll16(kb + (size_t)(k0_ + row_) * HD + uc_ * 8,                       \
              k_l + ((w * 64 + r_ * 512) << 3));                              \
    }
#define STAGE_V(k0_)                                                          \
    _Pragma("unroll") for (int r_ = 0; r_ < 4; ++r_) {                        \
        int row_ = irow0 + r_ * 32;                                           \
        int uc_ = iu0 ^ (row_ & 7);                                           \
        gll16(vb + (size_t)row_ * S + (k0_) + uc_ * 8,                        \
              v_l + ((w * 64 + r_ * 512) << 3));                              \
    }

    for (int pass = 0; pass < 2; ++pass) {
        const int t = pass ? (15 - slot) : slot;
        const int q0 = t * 128;

        bf16x8 qf[4][4];
#pragma unroll
        for (int mi = 0; mi < 4; ++mi)
#pragma unroll
            for (int kk = 0; kk < 4; ++kk)
                qf[mi][kk] = *(const bf16x8*)(qr +
                    ((size_t)bh * S + q0 + wq * 64 + mi * 16 + l16) * HD +
                    kk * 32 + lq * 8);
        f32x4 acco[4][2] = {};

        STAGE_K(0);
        STAGE_V(0);
        asm volatile("s_waitcnt vmcnt(0)" ::: "memory");
        BAR();

        for (int kt = 0; kt <= t; ++kt) {
            const int k0 = kt * 128;
            const bool st = kt < t;
            // ---- QK^T: S[64q (wq)][32k (wk4)] ----
            f32x4 accs[4][2] = {};
            __builtin_amdgcn_s_setprio(1);
#pragma unroll
            for (int kk = 0; kk < 4; ++kk)
#pragma unroll
                for (int ni = 0; ni < 2; ++ni) {
                    int row = wk4 * 32 + ni * 16 + l16;
                    bf16x8 kf = *(const bf16x8*)(k_l + row * 128 +
                                ((kk * 32 + lq * 8) ^ ((row & 7) << 3)));
#pragma unroll
                    for (int mi = 0; mi < 4; ++mi)
                        accs[mi][ni] = __builtin_amdgcn_mfma_f32_16x16x32_bf16(
                            qf[mi][kk], kf, accs[mi][ni], 0, 0, 0);
                }
            __builtin_amdgcn_s_setprio(0);
            // silu + causal mask -> s_l (shared across waves)
            const bool dg = (kt == t);
#pragma unroll
            for (int mi = 0; mi < 4; ++mi)
#pragma unroll
                for (int ni = 0; ni < 2; ++ni)
#pragma unroll
                    for (int r = 0; r < 4; ++r) {
                        int qrow = wq * 64 + mi * 16 + lq * 4 + r;
                        int krow = wk4 * 32 + ni * 16 + l16;
                        float vv = accs[mi][ni][r] * SCALE;
                        vv = (!dg || (k0 + krow <= q0 + qrow))
                                 ? vv * __builtin_amdgcn_rcpf(1.f + __expf(-vv))
                                 : 0.f;
                        s_l[qrow * 136 + krow] = f2b(vv);
                    }
            BAR();                       // s_l complete; k_l reads done
            if (st) STAGE_K(k0 + 128);   // overlaps PV
            if (st) asm volatile("s_waitcnt vmcnt(4)" ::: "memory");  // V(kt) landed
            else    asm volatile("s_waitcnt vmcnt(0)" ::: "memory");
            BAR();                       // v_l visible to all
            // ---- PV: out[64q (wq)][32d (wk4)] over 128 s ----
            __builtin_amdgcn_s_setprio(1);
#pragma unroll
            for (int kk = 0; kk < 4; ++kk) {
                bf16x8 sf[4];
#pragma unroll
                for (int mi = 0; mi < 4; ++mi)
                    sf[mi] = *(const bf16x8*)(s_l + (wq * 64 + mi * 16 + l16) * 136 +
                                              kk * 32 + lq * 8);
#pragma unroll
                for (int ni = 0; ni < 2; ++ni) {
                    int row = wk4 * 32 + ni * 16 + l16;   // d index
                    bf16x8 vf = *(const bf16x8*)(v_l + row * 128 +
                                ((kk * 32 + lq * 8) ^ ((row & 7) << 3)));
#pragma unroll
                    for (int mi = 0; mi < 4; ++mi)
                        acco[mi][ni] = __builtin_amdgcn_mfma_f32_16x16x32_bf16(
                            sf[mi], vf, acco[mi][ni], 0, 0, 0);
                }
            }
            __builtin_amdgcn_s_setprio(0);
            BAR();                       // v_l + s_l reads done
            if (st) {
                STAGE_V(k0 + 128);
                asm volatile("s_waitcnt vmcnt(4)" ::: "memory");  // K(kt+1) landed
            }
            BAR();                       // k_l(kt+1) visible
        }
        // epilogue: att rows (f32, stride ATT_LD)
#pragma unroll
        for (int mi = 0; mi < 4; ++mi)
#pragma unroll
            for (int ni = 0; ni < 2; ++ni)
#pragma unroll
                for (int r = 0; r < 4; ++r)
                    att[(size_t)(b * S + q0 + wq * 64 + mi * 16 + lq * 4 + r) * ATT_LD +
                        h * HD + wk4 * 32 + ni * 16 + l16] = acco[mi][ni][r];
    }
#undef STAGE_K
#undef STAGE_V
}

// ---------------- RMS-norm * norm_w * u (in place over u cols of qku) ----------------
__global__ __launch_bounds__(256)
void rms_mul(const float* __restrict__ att, u16* __restrict__ qku,
             const float* __restrict__ nw) {
    int row = blockIdx.x;
    int tid = threadIdx.x;
    const float* a = att + (size_t)row * ATT_LD + tid * 8;
    float4 v0 = *(const float4*)(a);
    float4 v1 = *(const float4*)(a + 4);
    float ss = v0.x * v0.x + v0.y * v0.y + v0.z * v0.z + v0.w * v0.w +
               v1.x * v1.x + v1.y * v1.y + v1.z * v1.z + v1.w * v1.w;
#pragma unroll
    for (int off = 32; off > 0; off >>= 1) ss += __shfl_down(ss, off, 64);
    __shared__ float red[4];
    int lane = tid & 63, w = tid >> 6;
    if (lane == 0) red[w] = ss;
    __syncthreads();
    float rs = rsqrtf((red[0] + red[1] + red[2] + red[3]) * (1.f / D) + 1e-5f);
    int col = tid * 8;
    u16* up = qku + (size_t)row * NQKU + 4096 + col;
    u16 ut[8];
    *(int4*)ut = *(const int4*)up;
    float f[8] = {v0.x, v0.y, v0.z, v0.w, v1.x, v1.y, v1.z, v1.w};
    u16 o[8];
#pragma unroll
    for (int j = 0; j < 8; j++)
        o[j] = f2b(f[j] * rs * nw[col + j] * b2f(ut[j]));
    *(int4*)up = *(int4*)o;
}

extern "C" void kernel_launch(void* const* d_in, const int* in_sizes, int n_in,
                              void* d_out, int out_size, void* d_ws, size_t ws_size,
                              hipStream_t stream) {
    const float* x  = (const float*)d_in[0];
    const float* fc = (const float*)d_in[1];
    const float* fs = (const float*)d_in[2];
    const float* wq = (const float*)d_in[3];
    const float* wk = (const float*)d_in[4];
    const float* wv = (const float*)d_in[5];
    const float* wu = (const float*)d_in[6];
    const float* wo = (const float*)d_in[7];
    const float* nw = (const float*)d_in[8];
    float* out = (float*)d_out;

    char* ws = (char*)d_ws;
    const size_t WSZ = (size_t)D * D * sizeof(u16);      // 8.39 MB
    u16* h_b  = (u16*)(ws);
    u16* wT   = (u16*)(ws + 2 * WSZ);                    // rows: q,k,u,v,o
    u16* qku  = (u16*)(ws + 7 * WSZ);                    // M x 6144
    u16* vt   = (u16*)(ws + 13 * WSZ);                   // (B,H,HD,S)
    u16* k_r  = (u16*)(ws + 15 * WSZ);                   // (B,H,S,HD)
    u16* q_r  = h_b;                                     // overlay (h consumed by GEMM)
    float* att = (float*)qku;                            // overlay q+k cols as f32

    silu_cast<<<M * D / 1024, 256, 0, stream>>>(x, h_b, M * D);
    dim3 wg(32, 32);
    wcast<<<wg, 256, 0, stream>>>(wq, wT + 0 * (size_t)D * D);
    wcast<<<wg, 256, 0, stream>>>(wk, wT + 1 * (size_t)D * D);
    wcast<<<wg, 256, 0, stream>>>(wu, wT + 2 * (size_t)D * D);
    wcast<<<wg, 256, 0, stream>>>(wv, wT + 3 * (size_t)D * D);
    wcast<<<wg, 256, 0, stream>>>(wo, wT + 4 * (size_t)D * D);

    gemm_qkuv<<<512, 512, 0, stream>>>(h_b, wT, qku, vt);

    reformat<<<dim3(32, 32), 256, 0, stream>>>(qku, fc, fs, q_r, k_r);
    hstu_attn<<<256, 512, 0, stream>>>(q_r, k_r, vt, att);
    rms_mul<<<M, 256, 0, stream>>>(att, qku, nw);
    gemm_bt_f32<<<dim3(D / 128, M / 128), 256, 0, stream>>>(
        qku + 4096, wT + 4 * (size_t)D * D, out, NQKU, D, D);
}